// Round 4
// baseline (213.832 us; speedup 1.0000x reference)
//
#include <hip/hip_runtime.h>
#include <cstdint>
#include <cstddef>

// CRF NLL forward. B=256, T=512, L=64. One wave per batch; lane j = label.
// Scaled linear-domain scan: alpha'_j = (sum_i alpha_i * E_ij) * exp(emit_j).
// R4 changes vs R3 (issue-count reduction; wave issues ~70% of cycles already):
//  - matvec uses packed fp32: Ecol held as float2 pairs, accumulation via
//    __builtin_elementwise_fma on <2 x float> -> v_pk_fma_f32 (2 MACs/inst).
//    Broadcast pair = 2 v_readlane. 96 insts vs 128 for the 4096-MAC matvec.
//  - all off-chain work (exp(emit), psum fma, ballot->l_cur, trow ds_read
//    issue, tsum fma) hoisted into the block preamble; the 4 unrolled steps
//    are pure matvec on the serial alpha chain.

constexpr int Bc = 256;
constexpr int Tc = 512;
constexpr int Lc = 64;

typedef float v2f __attribute__((ext_vector_type(2)));

__device__ __forceinline__ float lane_bcast(float v, int lane) {
    return __uint_as_float(__builtin_amdgcn_readlane(__float_as_uint(v), lane));
}

__global__ __launch_bounds__(64, 1) void crf_nll_kernel(
    const float* __restrict__ y_true,
    const float* __restrict__ y_pred,
    const float* __restrict__ trans,
    float* __restrict__ out)
{
    const int b = blockIdx.x;
    const int j = threadIdx.x;  // label index

    __shared__ float strans[Lc * Lc];

    // Ecol2[i] = { exp(trans[2i][j]), exp(trans[2i+1][j]) }  (lane j's column)
    v2f Ecol2[Lc / 2];
    #pragma unroll
    for (int i = 0; i < Lc / 2; ++i) {
        const float t0 = trans[(2 * i) * Lc + j];
        const float t1 = trans[(2 * i + 1) * Lc + j];
        Ecol2[i] = v2f{__expf(t0), __expf(t1)};
        strans[(2 * i) * Lc + j] = t0;
        strans[(2 * i + 1) * Lc + j] = t1;
    }
    __syncthreads();

    const float* yp = y_pred + (size_t)b * Tc * Lc + j;
    const float* yt = y_true + (size_t)b * Tc * Lc + j;

    // row 0
    const float yp0 = yp[0], yt0 = yt[0];
    float psum = yp0 * yt0;
    float tsum = 0.0f;
    float c = lane_bcast(yp0, 0);      // lane-0 reference; spread <= e^11, safe
    float alpha = __expf(yp0 - c);

    int l_last = (int)__builtin_ctzll(__ballot(yt0 > 0.5f));
    float trow0 = strans[l_last * Lc + j];   // strans[l_{t-1}] entering block

    // pure matvec step on the serial chain: alpha = (alpha . E) * F
    auto matvec = [&](float F) {
        v2f s0 = {0.f, 0.f}, s1 = {0.f, 0.f}, s2 = {0.f, 0.f}, s3 = {0.f, 0.f};
        #pragma unroll
        for (int i = 0; i < Lc / 2; i += 4) {
            v2f a0 = v2f{lane_bcast(alpha, 2 * i + 0), lane_bcast(alpha, 2 * i + 1)};
            v2f a1 = v2f{lane_bcast(alpha, 2 * i + 2), lane_bcast(alpha, 2 * i + 3)};
            v2f a2 = v2f{lane_bcast(alpha, 2 * i + 4), lane_bcast(alpha, 2 * i + 5)};
            v2f a3 = v2f{lane_bcast(alpha, 2 * i + 6), lane_bcast(alpha, 2 * i + 7)};
            s0 = __builtin_elementwise_fma(a0, Ecol2[i + 0], s0);
            s1 = __builtin_elementwise_fma(a1, Ecol2[i + 1], s1);
            s2 = __builtin_elementwise_fma(a2, Ecol2[i + 2], s2);
            s3 = __builtin_elementwise_fma(a3, Ecol2[i + 3], s3);
        }
        const v2f s = (s0 + s1) + (s2 + s3);
        alpha = (s.x + s.y) * F;
    };

    auto renorm = [&]() {
        const float s = lane_bcast(alpha, 0);
        alpha *= (1.0f / s);
        c += __logf(s);
    };

    // prefetch rows 1..4
    float a_yp = yp[1 * Lc], a_yt = yt[1 * Lc];
    float b_yp = yp[2 * Lc], b_yt = yt[2 * Lc];
    float c_yp = yp[3 * Lc], c_yt = yt[3 * Lc];
    float d_yp = yp[4 * Lc], d_yt = yt[4 * Lc];

    int t = 1;
    #pragma unroll 1
    for (; t + 7 < Tc; t += 4) {
        // ---- block preamble: everything off the alpha chain ----
        // prefetch rows t+4..t+7
        const float na_yp = yp[(t + 4) * Lc], na_yt = yt[(t + 4) * Lc];
        const float nb_yp = yp[(t + 5) * Lc], nb_yt = yt[(t + 5) * Lc];
        const float nc_yp = yp[(t + 6) * Lc], nc_yt = yt[(t + 6) * Lc];
        const float nd_yp = yp[(t + 7) * Lc], nd_yt = yt[(t + 7) * Lc];

        const float Fa = __expf(a_yp), Fb = __expf(b_yp);
        const float Fc = __expf(c_yp), Fd = __expf(d_yp);

        psum = fmaf(a_yp, a_yt, psum);
        psum = fmaf(b_yp, b_yt, psum);
        psum = fmaf(c_yp, c_yt, psum);
        psum = fmaf(d_yp, d_yt, psum);

        const int la = (int)__builtin_ctzll(__ballot(a_yt > 0.5f));
        const int lb = (int)__builtin_ctzll(__ballot(b_yt > 0.5f));
        const int lc = (int)__builtin_ctzll(__ballot(c_yt > 0.5f));
        const int ld = (int)__builtin_ctzll(__ballot(d_yt > 0.5f));

        const float trow1 = strans[la * Lc + j];
        const float trow2 = strans[lb * Lc + j];
        const float trow3 = strans[lc * Lc + j];
        const float trow4 = strans[ld * Lc + j];   // next block's trow0

        tsum = fmaf(a_yt, trow0, tsum);
        tsum = fmaf(b_yt, trow1, tsum);
        tsum = fmaf(c_yt, trow2, tsum);
        tsum = fmaf(d_yt, trow3, tsum);
        trow0 = trow4;

        // ---- serial chain: 4 pure matvec steps + renorm ----
        matvec(Fa);
        matvec(Fb);
        matvec(Fc);
        matvec(Fd);
        renorm();   // growth over 4 steps < e^45, fp32-safe

        a_yp = na_yp; a_yt = na_yt;
        b_yp = nb_yp; b_yt = nb_yt;
        c_yp = nc_yp; c_yt = nc_yt;
        d_yp = nd_yp; d_yt = nd_yt;
    }

    // tail: rows t..511 (t == 505); a..d hold rows 505..508
    {
        const float e_yp = yp[(t + 4) * Lc], e_yt = yt[(t + 4) * Lc];
        const float f_yp = yp[(t + 5) * Lc], f_yt = yt[(t + 5) * Lc];
        const float g_yp = yp[(t + 6) * Lc], g_yt = yt[(t + 6) * Lc];

        float rp[7] = {a_yp, b_yp, c_yp, d_yp, e_yp, f_yp, g_yp};
        float rt[7] = {a_yt, b_yt, c_yt, d_yt, e_yt, f_yt, g_yt};
        #pragma unroll
        for (int k = 0; k < 7; ++k) {
            psum = fmaf(rp[k], rt[k], psum);
            tsum = fmaf(rt[k], trow0, tsum);
            const int lcur = (int)__builtin_ctzll(__ballot(rt[k] > 0.5f));
            trow0 = strans[lcur * Lc + j];
            matvec(__expf(rp[k]));
            if ((k & 3) == 3) renorm();
        }
    }

    // final cross-lane reductions (once)
    float asum = alpha;
    #pragma unroll
    for (int k = 1; k < 64; k <<= 1) asum += __shfl_xor(asum, k);
    #pragma unroll
    for (int k = 1; k < 64; k <<= 1) psum += __shfl_xor(psum, k);
    #pragma unroll
    for (int k = 1; k < 64; k <<= 1) tsum += __shfl_xor(tsum, k);

    if (j == 0) {
        const float log_norm = c + __logf(asum);
        out[b] = -(psum + tsum - log_norm);
    }
}

extern "C" void kernel_launch(void* const* d_in, const int* in_sizes, int n_in,
                              void* d_out, int out_size, void* d_ws, size_t ws_size,
                              hipStream_t stream) {
    const float* y_true = (const float*)d_in[0];
    const float* y_pred = (const float*)d_in[1];
    const float* trans  = (const float*)d_in[2];
    float* outp         = (float*)d_out;
    crf_nll_kernel<<<dim3(Bc), dim3(Lc), 0, stream>>>(y_true, y_pred, trans, outp);
}

// Round 6
// 200.896 us; speedup vs baseline: 1.0644x; 1.0644x over previous
//
#include <hip/hip_runtime.h>
#include <hip/hip_bf16.h>
#include <cstdint>
#include <cstddef>

// CRF NLL forward. B=256, T=512, L=64. One wave per batch.
// R6 = R5 with the __builtin_bit_cast-on-__hip_bfloat162 compile error fixed
// (pack via __builtin_memcpy). Structure:
//   MFMA (16x16x32 bf16) matvec, replicated-column state.
//   alpha kept as B-operand frags (bf16, replicated over n=lane&15);
//   D = A*B gives alpha'[m] in C/D layout; D feeds the NEXT step's B operand
//   with pure per-lane register packing: the index permutation sigma is
//   absorbed into stationary A: A[m][k] = exp(trans[sigma(k)][m]).
//   Emit scale F (with lag-3 renorm factor folded in off-chain) applied in
//   fp32 via LDS ds_read_b128 broadcast.
// Layouts (HW-verified m89/m120): C/D col=lane&15,row=4*(lane>>4)+reg;
//   A[m=lane&15][k=8*(lane>>4)+j]; B[k=8*(lane>>4)+j][n=lane&15].

constexpr int Bc = 256, Tc = 512, Lc = 64;

typedef __attribute__((ext_vector_type(8))) short v8s;   // 8 bf16 = 4 VGPR
typedef __attribute__((ext_vector_type(4))) float v4f;
typedef __attribute__((ext_vector_type(4))) unsigned int v4u;

__device__ __forceinline__ float lane_bcast(float v, int lane) {
    return __uint_as_float(__builtin_amdgcn_readlane(__float_as_uint(v), lane));
}
__device__ __forceinline__ unsigned pk2(float x, float y) {
    __hip_bfloat162 h = __float22bfloat162_rn(make_float2(x, y));
    unsigned r;
    __builtin_memcpy(&r, &h, 4);
    return r;
}
__device__ __forceinline__ v8s as_v8s(v4u u) {
    v8s r;
    __builtin_memcpy(&r, &u, 16);
    return r;
}

__global__ __launch_bounds__(64, 1) void crf_nll_kernel(
    const float* __restrict__ y_true,
    const float* __restrict__ y_pred,
    const float* __restrict__ trans,
    float* __restrict__ out)
{
    const int b    = blockIdx.x;
    const int lane = threadIdx.x;
    const int m16  = lane & 15;   // MFMA m/n index
    const int q    = lane >> 4;   // MFMA quad

    __shared__ float strans[Lc * Lc];
    __shared__ alignas(16) float fbuf[2][Lc];

    #pragma unroll 4
    for (int i = 0; i < Lc; ++i) strans[i * Lc + lane] = trans[i * Lc + lane];
    __syncthreads();

    // Stationary A frags: A[T][cc], element j = exp(trans[sigma][16T+m16]),
    // sigma = (j&3) + 4q + 16*(j>>2) + 32*cc.
    v8s Afrag[4][2];
    #pragma unroll
    for (int T = 0; T < 4; ++T) {
        #pragma unroll
        for (int cc = 0; cc < 2; ++cc) {
            float e[8];
            #pragma unroll
            for (int jj = 0; jj < 8; ++jj) {
                const int sig = (jj & 3) + 4 * q + 16 * (jj >> 2) + 32 * cc;
                e[jj] = __expf(strans[sig * Lc + 16 * T + m16]);
            }
            v4u u;
            u.x = pk2(e[0], e[1]); u.y = pk2(e[2], e[3]);
            u.z = pk2(e[4], e[5]); u.w = pk2(e[6], e[7]);
            Afrag[T][cc] = as_v8s(u);
        }
    }

    const float* yp = y_pred + (size_t)b * Tc * Lc + lane;
    const float* yt = y_true + (size_t)b * Tc * Lc + lane;

    // row 0: scores init + alpha0 row into fbuf[0]
    const float yp0 = yp[0], yt0 = yt[0];
    float psum = yp0 * yt0, tsum = 0.0f;
    float c = lane_bcast(yp0, 0);             // reference; spread <= e^11
    fbuf[0][lane] = __expf(yp0 - c);
    const int l0 = (int)__builtin_ctzll(__ballot(yt0 > 0.5f));
    float trow = strans[l0 * Lc + lane];

    // prefetch rows 1..4
    float a_yp = yp[1 * Lc], a_yt = yt[1 * Lc];
    float b_yp = yp[2 * Lc], b_yt = yt[2 * Lc];
    float c_yp = yp[3 * Lc], c_yt = yt[3 * Lc];
    float d_yp = yp[4 * Lc], d_yt = yt[4 * Lc];

    fbuf[1][lane] = __expf(a_yp);             // F row for step 1 (no renorm)
    __syncthreads();

    // initial B frags from alpha0 row: chunk cc element j = x[(j&3)+4q+16*(j>>2)+32cc]
    v8s Bfr[2];
    #pragma unroll
    for (int cc = 0; cc < 2; ++cc) {
        const v4f lo = *(const v4f*)&fbuf[0][32 * cc + 4 * q];
        const v4f hi = *(const v4f*)&fbuf[0][32 * cc + 16 + 4 * q];
        v4u u;
        u.x = pk2(lo.x, lo.y); u.y = pk2(lo.z, lo.w);
        u.z = pk2(hi.x, hi.y); u.w = pk2(hi.z, hi.w);
        Bfr[cc] = as_v8s(u);
    }

    float Pprev[16];
    #pragma unroll
    for (int i = 0; i < 16; ++i) Pprev[i] = 1.0f;   // s unused until valid
    float s_pipe = 1.0f;
    const v4f z4 = {0.f, 0.f, 0.f, 0.f};

    auto step = [&](int i, float ypc, float ytc, float ypn,
                    bool build_next, bool renorm_next) {
        // ---- off-chain: scores ----
        psum = fmaf(ypc, ytc, psum);
        tsum = fmaf(ytc, trow, tsum);
        const int lcur = (int)__builtin_ctzll(__ballot(ytc > 0.5f));
        trow = strans[lcur * Lc + lane];
        // ---- off-chain: F row for step i+1 (renorm folded in, lag-3 s) ----
        if (build_next) {
            float f = __expf(ypn);
            if (renorm_next) { f *= (1.0f / s_pipe); c += __logf(s_pipe); }
            fbuf[(i + 1) & 1][lane] = f;
        }
        // ---- off-chain: s pipeline from P_{i-1} (wave-uniform) ----
        {
            float ss = (((Pprev[0] + Pprev[1]) + (Pprev[2] + Pprev[3]))
                      + ((Pprev[4] + Pprev[5]) + (Pprev[6] + Pprev[7])))
                     + (((Pprev[8] + Pprev[9]) + (Pprev[10] + Pprev[11]))
                      + ((Pprev[12] + Pprev[13]) + (Pprev[14] + Pprev[15])));
            ss += __shfl_xor(ss, 16);
            ss += __shfl_xor(ss, 32);
            s_pipe = ss;
        }
        // ---- on-chain: 8 MFMA (4 tiles x 2 K-chunks) ----
        v4f acc0 = __builtin_amdgcn_mfma_f32_16x16x32_bf16(Afrag[0][0], Bfr[0], z4, 0, 0, 0);
        v4f acc1 = __builtin_amdgcn_mfma_f32_16x16x32_bf16(Afrag[1][0], Bfr[0], z4, 0, 0, 0);
        v4f acc2 = __builtin_amdgcn_mfma_f32_16x16x32_bf16(Afrag[2][0], Bfr[0], z4, 0, 0, 0);
        v4f acc3 = __builtin_amdgcn_mfma_f32_16x16x32_bf16(Afrag[3][0], Bfr[0], z4, 0, 0, 0);
        acc0 = __builtin_amdgcn_mfma_f32_16x16x32_bf16(Afrag[0][1], Bfr[1], acc0, 0, 0, 0);
        acc1 = __builtin_amdgcn_mfma_f32_16x16x32_bf16(Afrag[1][1], Bfr[1], acc1, 0, 0, 0);
        acc2 = __builtin_amdgcn_mfma_f32_16x16x32_bf16(Afrag[2][1], Bfr[1], acc2, 0, 0, 0);
        acc3 = __builtin_amdgcn_mfma_f32_16x16x32_bf16(Afrag[3][1], Bfr[1], acc3, 0, 0, 0);
        // ---- on-chain: F scale (LDS broadcast, conflict-free) ----
        const v4f F0 = *(const v4f*)&fbuf[i & 1][ 0 + 4 * q];
        const v4f F1 = *(const v4f*)&fbuf[i & 1][16 + 4 * q];
        const v4f F2 = *(const v4f*)&fbuf[i & 1][32 + 4 * q];
        const v4f F3 = *(const v4f*)&fbuf[i & 1][48 + 4 * q];
        const v4f P0 = acc0 * F0, P1 = acc1 * F1, P2 = acc2 * F2, P3 = acc3 * F3;
        // ---- on-chain: repack D -> next B (pure per-lane) ----
        {
            v4u u;
            u.x = pk2(P0.x, P0.y); u.y = pk2(P0.z, P0.w);
            u.z = pk2(P1.x, P1.y); u.w = pk2(P1.z, P1.w);
            Bfr[0] = as_v8s(u);
        }
        {
            v4u u;
            u.x = pk2(P2.x, P2.y); u.y = pk2(P2.z, P2.w);
            u.z = pk2(P3.x, P3.y); u.w = pk2(P3.z, P3.w);
            Bfr[1] = as_v8s(u);
        }
        Pprev[0]  = P0.x; Pprev[1]  = P0.y; Pprev[2]  = P0.z; Pprev[3]  = P0.w;
        Pprev[4]  = P1.x; Pprev[5]  = P1.y; Pprev[6]  = P1.z; Pprev[7]  = P1.w;
        Pprev[8]  = P2.x; Pprev[9]  = P2.y; Pprev[10] = P2.z; Pprev[11] = P2.w;
        Pprev[12] = P3.x; Pprev[13] = P3.y; Pprev[14] = P3.z; Pprev[15] = P3.w;
    };

    int t0 = 1;
    #pragma unroll 1
    for (; t0 + 6 < Tc; t0 += 4) {          // t0 = 1..505, steps 1..508
        const int r4 = min(t0 + 4, Tc - 1) * Lc;
        const int r5 = min(t0 + 5, Tc - 1) * Lc;
        const int r6 = min(t0 + 6, Tc - 1) * Lc;
        const int r7 = min(t0 + 7, Tc - 1) * Lc;
        const float na_yp = yp[r4], na_yt = yt[r4];
        const float nb_yp = yp[r5], nb_yt = yt[r5];
        const float nc_yp = yp[r6], nc_yt = yt[r6];
        const float nd_yp = yp[r7], nd_yt = yt[r7];

        step(t0 + 0, a_yp, a_yt, b_yp,  true, false);
        step(t0 + 1, b_yp, b_yt, c_yp,  true, false);
        step(t0 + 2, c_yp, c_yt, d_yp,  true, true );  // F for step t0+3 (==0 mod 4)
        step(t0 + 3, d_yp, d_yt, na_yp, true, false);

        a_yp = na_yp; a_yt = na_yt;
        b_yp = nb_yp; b_yt = nb_yt;
        c_yp = nc_yp; c_yt = nc_yt;
        d_yp = nd_yp; d_yt = nd_yt;
    }
    // tail: t0 == 509; slots a..c hold rows 509..511
    step(509, a_yp, a_yt, b_yp, true,  false);
    step(510, b_yp, b_yt, c_yp, true,  false);
    step(511, c_yp, c_yt, 0.0f, false, false);

    // final total = sum over labels of alpha_511 (Pprev, replicated over n)
    float ftot = (((Pprev[0] + Pprev[1]) + (Pprev[2] + Pprev[3]))
                + ((Pprev[4] + Pprev[5]) + (Pprev[6] + Pprev[7])))
               + (((Pprev[8] + Pprev[9]) + (Pprev[10] + Pprev[11]))
                + ((Pprev[12] + Pprev[13]) + (Pprev[14] + Pprev[15])));
    ftot += __shfl_xor(ftot, 16);
    ftot += __shfl_xor(ftot, 32);
    const float log_norm = c + __logf(ftot);

    #pragma unroll
    for (int k = 1; k < 64; k <<= 1) psum += __shfl_xor(psum, k);
    #pragma unroll
    for (int k = 1; k < 64; k <<= 1) tsum += __shfl_xor(tsum, k);

    if (lane == 0) out[b] = -(psum + tsum - log_norm);
}

extern "C" void kernel_launch(void* const* d_in, const int* in_sizes, int n_in,
                              void* d_out, int out_size, void* d_ws, size_t ws_size,
                              hipStream_t stream) {
    const float* y_true = (const float*)d_in[0];
    const float* y_pred = (const float*)d_in[1];
    const float* trans  = (const float*)d_in[2];
    float* outp         = (float*)d_out;
    crf_nll_kernel<<<dim3(Bc), dim3(Lc), 0, stream>>>(y_true, y_pred, trans, outp);
}

// Round 8
// 198.429 us; speedup vs baseline: 1.0776x; 1.0124x over previous
//
#include <hip/hip_runtime.h>
#include <hip/hip_bf16.h>
#include <cstdint>
#include <cstddef>

// CRF NLL forward. B=256, T=512, L=64. One wave per batch.
// R8 = R7 with the drift-correction instability fixed:
//   inv_s is applied to ONE row (rsub==0) of the next F block, so the
//   log-drift recurrence is u_{k+1} = d - u_k (stable), matching c += log(sc).
//   R7 applied it to all 4 rows -> u_{k+1} = d - 4u_k -> 4^k blowup -> NaN.
// Core (verified R6): MFMA 16x16x32 bf16, replicated-column state, sigma
// absorbed into stationary A; per-step kappa fold (emit[0]+ln64) into F.

constexpr int Bc = 256, Tc = 512, Lc = 64;
#define LOG64F 4.1588830833596715f

typedef __attribute__((ext_vector_type(8))) short v8s;   // 8 bf16
typedef __attribute__((ext_vector_type(4))) float v4f;
typedef __attribute__((ext_vector_type(4))) unsigned int v4u;

__device__ __forceinline__ float lane_bcast(float v, int lane) {
    return __uint_as_float(__builtin_amdgcn_readlane(__float_as_uint(v), lane));
}
__device__ __forceinline__ int lane_bcast_i(int v, int lane) {
    return __builtin_amdgcn_readlane(v, lane);
}
__device__ __forceinline__ unsigned pk2(float x, float y) {
    __hip_bfloat162 h = __float22bfloat162_rn(make_float2(x, y));
    unsigned r; __builtin_memcpy(&r, &h, 4); return r;
}
__device__ __forceinline__ v8s as_v8s(v4u u) {
    v8s r; __builtin_memcpy(&r, &u, 16); return r;
}

__global__ __launch_bounds__(64, 1) void crf_nll_kernel(
    const float* __restrict__ y_true,
    const float* __restrict__ y_pred,
    const float* __restrict__ trans,
    float* __restrict__ out)
{
    const int b    = blockIdx.x;
    const int lane = threadIdx.x;
    const int m16  = lane & 15;   // MFMA m/n
    const int q    = lane >> 4;   // MFMA quad
    const int rsub = lane >> 4;   // x4-layout row subgroup
    const int csub = lane & 15;   // x4-layout col4 subgroup

    __shared__ float strans[Lc * Lc];
    __shared__ alignas(16) float fbuf[2][4][Lc];
    __shared__ alignas(16) float arow[Lc];

    // stage trans (16 KB) with 16 in-flight dwordx4 loads
    {
        const v4f* t4 = (const v4f*)trans;
        #pragma unroll
        for (int k = 0; k < 16; ++k) {
            v4f v = t4[k * 64 + lane];
            *(v4f*)&strans[(k * 64 + lane) * 4] = v;
        }
    }
    __syncthreads();

    // Stationary A frags (verified R6 mapping): elem j = exp(trans[sigma][16T+m16]),
    // sigma = (j&3) + 4q + 16*(j>>2) + 32*cc.
    v8s Afrag[4][2];
    #pragma unroll
    for (int T = 0; T < 4; ++T) {
        #pragma unroll
        for (int cc = 0; cc < 2; ++cc) {
            float e[8];
            #pragma unroll
            for (int jj = 0; jj < 8; ++jj) {
                const int sig = (jj & 3) + 4 * q + 16 * (jj >> 2) + 32 * cc;
                e[jj] = __expf(strans[sig * Lc + 16 * T + m16]);
            }
            v4u u;
            u.x = pk2(e[0], e[1]); u.y = pk2(e[2], e[3]);
            u.z = pk2(e[4], e[5]); u.w = pk2(e[6], e[7]);
            Afrag[T][cc] = as_v8s(u);
        }
    }

    const float* yp = y_pred + (size_t)b * Tc * Lc;
    const float* yt = y_true + (size_t)b * Tc * Lc;
    const v4f* yp4 = (const v4f*)yp;   // idx = row*16 + col4
    const v4f* yt4 = (const v4f*)yt;

    // ---- row 0 init ----
    const float yp0 = yp[lane], yt0 = yt[lane];
    float psum = yp0 * yt0, tsum = 0.0f;
    float c = lane_bcast(yp0, 0);
    arow[lane] = __expf(yp0 - c);
    int lbl_carry = (int)__builtin_ctzll(__ballot(yt0 > 0.5f));   // l_0

    auto ld4 = [&](const v4f* p, int baseRow) -> v4f {
        int r = baseRow + rsub; r = (r < Tc - 1) ? r : (Tc - 1);
        return p[r * 16 + csub];
    };

    // x4 stages: cur=rows 1..4, next=5..8, next2=9..12
    v4f cyp = ld4(yp4, 1), cyt = ld4(yt4, 1);
    v4f nyp = ld4(yp4, 5), nyt = ld4(yt4, 5);
    v4f myp = ld4(yp4, 9), myt = ld4(yt4, 9);

    // ---- prologue F rows 1..4 ----
    {
        const float k0 = lane_bcast(cyp.x, 0)  + LOG64F;
        const float k1 = lane_bcast(cyp.x, 16) + LOG64F;
        const float k2 = lane_bcast(cyp.x, 32) + LOG64F;
        const float k3 = lane_bcast(cyp.x, 48) + LOG64F;
        c += ((k0 + k1) + (k2 + k3));
        const float kk = (rsub & 1) ? ((rsub & 2) ? k3 : k1)
                                    : ((rsub & 2) ? k2 : k0);
        v4f f;
        f.x = __expf(cyp.x - kk); f.y = __expf(cyp.y - kk);
        f.z = __expf(cyp.z - kk); f.w = __expf(cyp.w - kk);
        *(v4f*)&fbuf[0][rsub][4 * csub] = f;
    }
    __syncthreads();

    // ---- initial B frags from arow (verified R6 mapping) ----
    v8s Bfr[2];
    #pragma unroll
    for (int cc = 0; cc < 2; ++cc) {
        const v4f lo = *(const v4f*)&arow[32 * cc + 4 * q];
        const v4f hi = *(const v4f*)&arow[32 * cc + 16 + 4 * q];
        v4u u;
        u.x = pk2(lo.x, lo.y); u.y = pk2(lo.z, lo.w);
        u.z = pk2(hi.x, hi.y); u.w = pk2(hi.z, hi.w);
        Bfr[cc] = as_v8s(u);
    }

    const v4f z4 = {0.f, 0.f, 0.f, 0.f};
    v4f P0 = z4, P1 = z4, P2 = z4, P3 = z4;
    int par = 0;

    #pragma unroll 1
    for (int t0 = 1; t0 <= 505; t0 += 4) {
        // ---- preamble: issue loads rows t0+12..t0+15 ----
        const v4f lyp = ld4(yp4, t0 + 12), lyt = ld4(yt4, t0 + 12);

        // ---- scores for cur rows t0..t0+3 ----
        psum = fmaf(cyp.x, cyt.x, psum); psum = fmaf(cyp.y, cyt.y, psum);
        psum = fmaf(cyp.z, cyt.z, psum); psum = fmaf(cyp.w, cyt.w, psum);
        {
            const float has = fmaxf(fmaxf(cyt.x, cyt.y), fmaxf(cyt.z, cyt.w));
            int lidx = 0;
            lidx = (cyt.y > 0.5f) ? 1 : lidx;
            lidx = (cyt.z > 0.5f) ? 2 : lidx;
            lidx = (cyt.w > 0.5f) ? 3 : lidx;
            const unsigned long long m = __ballot(has > 0.5f);
            const int ln0 = (int)__builtin_ctz((unsigned)(m & 0xFFFFull));
            const int ln1 = (int)__builtin_ctz((unsigned)((m >> 16) & 0xFFFFull));
            const int ln2 = (int)__builtin_ctz((unsigned)((m >> 32) & 0xFFFFull));
            const int ln3 = (int)__builtin_ctz((unsigned)(m >> 48));
            const int lbl0 = 4 * ln0 + lane_bcast_i(lidx, ln0);
            const int lbl1 = 4 * ln1 + lane_bcast_i(lidx, 16 + ln1);
            const int lbl2 = 4 * ln2 + lane_bcast_i(lidx, 32 + ln2);
            const int lbl3 = 4 * ln3 + lane_bcast_i(lidx, 48 + ln3);
            const int lpA = (rsub & 2) ? lbl1 : lbl_carry;  // rsub 0,2
            const int lpB = (rsub & 2) ? lbl2 : lbl0;       // rsub 1,3
            const int lp  = (rsub & 1) ? lpB : lpA;
            lbl_carry = lbl3;
            const v4f tr = *(const v4f*)&strans[lp * Lc + 4 * csub];
            tsum = fmaf(cyt.x, tr.x, tsum); tsum = fmaf(cyt.y, tr.y, tsum);
            tsum = fmaf(cyt.z, tr.z, tsum); tsum = fmaf(cyt.w, tr.w, tsum);
        }

        // ---- 4 pure MFMA steps ----
        #pragma unroll
        for (int s = 0; s < 4; ++s) {
            const v4f F0 = *(const v4f*)&fbuf[par][s][ 0 + 4 * q];
            const v4f F1 = *(const v4f*)&fbuf[par][s][16 + 4 * q];
            const v4f F2 = *(const v4f*)&fbuf[par][s][32 + 4 * q];
            const v4f F3 = *(const v4f*)&fbuf[par][s][48 + 4 * q];
            v4f a0 = __builtin_amdgcn_mfma_f32_16x16x32_bf16(Afrag[0][0], Bfr[0], z4, 0, 0, 0);
            v4f a1 = __builtin_amdgcn_mfma_f32_16x16x32_bf16(Afrag[1][0], Bfr[0], z4, 0, 0, 0);
            v4f a2 = __builtin_amdgcn_mfma_f32_16x16x32_bf16(Afrag[2][0], Bfr[0], z4, 0, 0, 0);
            v4f a3 = __builtin_amdgcn_mfma_f32_16x16x32_bf16(Afrag[3][0], Bfr[0], z4, 0, 0, 0);
            a0 = __builtin_amdgcn_mfma_f32_16x16x32_bf16(Afrag[0][1], Bfr[1], a0, 0, 0, 0);
            a1 = __builtin_amdgcn_mfma_f32_16x16x32_bf16(Afrag[1][1], Bfr[1], a1, 0, 0, 0);
            a2 = __builtin_amdgcn_mfma_f32_16x16x32_bf16(Afrag[2][1], Bfr[1], a2, 0, 0, 0);
            a3 = __builtin_amdgcn_mfma_f32_16x16x32_bf16(Afrag[3][1], Bfr[1], a3, 0, 0, 0);
            P0 = a0 * F0; P1 = a1 * F1; P2 = a2 * F2; P3 = a3 * F3;
            {
                v4u u;
                u.x = pk2(P0.x, P0.y); u.y = pk2(P0.z, P0.w);
                u.z = pk2(P1.x, P1.y); u.w = pk2(P1.z, P1.w);
                Bfr[0] = as_v8s(u);
            }
            {
                v4u u;
                u.x = pk2(P2.x, P2.y); u.y = pk2(P2.z, P2.w);
                u.z = pk2(P3.x, P3.y); u.w = pk2(P3.z, P3.w);
                Bfr[1] = as_v8s(u);
            }
        }

        // ---- postamble: drift correction (ONE row) + F build rows t0+4..t0+7 ----
        {
            const float sc = lane_bcast(P0.x, 0);   // alpha~[0], fresh
            const float inv_s = 1.0f / sc;
            c += __logf(sc);
            const float k0 = lane_bcast(nyp.x, 0)  + LOG64F;
            const float k1 = lane_bcast(nyp.x, 16) + LOG64F;
            const float k2 = lane_bcast(nyp.x, 32) + LOG64F;
            const float k3 = lane_bcast(nyp.x, 48) + LOG64F;
            c += ((k0 + k1) + k2);
            if (t0 < 505) c += k3;                  // phantom row 512 guard
            const float kk = (rsub & 1) ? ((rsub & 2) ? k3 : k1)
                                        : ((rsub & 2) ? k2 : k0);
            // stability: correction applied to row rsub==0 ONLY
            const float sc0 = (rsub == 0) ? inv_s : 1.0f;
            v4f f;
            f.x = __expf(cyp.x * 0.0f + nyp.x - kk) * sc0;  // keep simple exprs
            f.y = __expf(nyp.y - kk) * sc0;
            f.z = __expf(nyp.z - kk) * sc0;
            f.w = __expf(nyp.w - kk) * sc0;
            *(v4f*)&fbuf[par ^ 1][rsub][4 * csub] = f;
        }
        par ^= 1;
        cyp = nyp; cyt = nyt; nyp = myp; nyt = myt; myp = lyp; myt = lyt;
    }

    // ---- tail: scores rows 509..511 (cur = rows 509..512, rsub==3 phantom) ----
    {
        float pd = cyp.x * cyt.x;
        pd = fmaf(cyp.y, cyt.y, pd); pd = fmaf(cyp.z, cyt.z, pd); pd = fmaf(cyp.w, cyt.w, pd);
        const float has = fmaxf(fmaxf(cyt.x, cyt.y), fmaxf(cyt.z, cyt.w));
        int lidx = 0;
        lidx = (cyt.y > 0.5f) ? 1 : lidx;
        lidx = (cyt.z > 0.5f) ? 2 : lidx;
        lidx = (cyt.w > 0.5f) ? 3 : lidx;
        const unsigned long long m = __ballot(has > 0.5f);
        const int ln0 = (int)__builtin_ctz((unsigned)(m & 0xFFFFull));
        const int ln1 = (int)__builtin_ctz((unsigned)((m >> 16) & 0xFFFFull));
        const int lbl0 = 4 * ln0 + lane_bcast_i(lidx, ln0);
        const int lbl1 = 4 * ln1 + lane_bcast_i(lidx, 16 + ln1);
        const int lpA = (rsub & 2) ? lbl1 : lbl_carry;  // rsub 0,2
        const int lp  = (rsub & 1) ? lbl0 : lpA;        // rsub 1 (rsub3 masked)
        const v4f tr = *(const v4f*)&strans[lp * Lc + 4 * csub];
        float td = cyt.x * tr.x;
        td = fmaf(cyt.y, tr.y, td); td = fmaf(cyt.z, tr.z, td); td = fmaf(cyt.w, tr.w, td);
        if (rsub < 3) { psum += pd; tsum += td; }
    }

    // ---- tail steps 509..511 ----
    #pragma unroll
    for (int s = 0; s < 3; ++s) {
        const v4f F0 = *(const v4f*)&fbuf[par][s][ 0 + 4 * q];
        const v4f F1 = *(const v4f*)&fbuf[par][s][16 + 4 * q];
        const v4f F2 = *(const v4f*)&fbuf[par][s][32 + 4 * q];
        const v4f F3 = *(const v4f*)&fbuf[par][s][48 + 4 * q];
        v4f a0 = __builtin_amdgcn_mfma_f32_16x16x32_bf16(Afrag[0][0], Bfr[0], z4, 0, 0, 0);
        v4f a1 = __builtin_amdgcn_mfma_f32_16x16x32_bf16(Afrag[1][0], Bfr[0], z4, 0, 0, 0);
        v4f a2 = __builtin_amdgcn_mfma_f32_16x16x32_bf16(Afrag[2][0], Bfr[0], z4, 0, 0, 0);
        v4f a3 = __builtin_amdgcn_mfma_f32_16x16x32_bf16(Afrag[3][0], Bfr[0], z4, 0, 0, 0);
        a0 = __builtin_amdgcn_mfma_f32_16x16x32_bf16(Afrag[0][1], Bfr[1], a0, 0, 0, 0);
        a1 = __builtin_amdgcn_mfma_f32_16x16x32_bf16(Afrag[1][1], Bfr[1], a1, 0, 0, 0);
        a2 = __builtin_amdgcn_mfma_f32_16x16x32_bf16(Afrag[2][1], Bfr[1], a2, 0, 0, 0);
        a3 = __builtin_amdgcn_mfma_f32_16x16x32_bf16(Afrag[3][1], Bfr[1], a3, 0, 0, 0);
        P0 = a0 * F0; P1 = a1 * F1; P2 = a2 * F2; P3 = a3 * F3;
        {
            v4u u;
            u.x = pk2(P0.x, P0.y); u.y = pk2(P0.z, P0.w);
            u.z = pk2(P1.x, P1.y); u.w = pk2(P1.z, P1.w);
            Bfr[0] = as_v8s(u);
        }
        {
            v4u u;
            u.x = pk2(P2.x, P2.y); u.y = pk2(P2.z, P2.w);
            u.z = pk2(P3.x, P3.y); u.w = pk2(P3.z, P3.w);
            Bfr[1] = as_v8s(u);
        }
    }

    // ---- finalize ----
    float ftot = (((P0.x + P0.y) + (P0.z + P0.w)) + ((P1.x + P1.y) + (P1.z + P1.w)))
               + (((P2.x + P2.y) + (P2.z + P2.w)) + ((P3.x + P3.y) + (P3.z + P3.w)));
    ftot += __shfl_xor(ftot, 16);
    ftot += __shfl_xor(ftot, 32);
    const float log_norm = c + __logf(ftot);

    #pragma unroll
    for (int k = 1; k < 64; k <<= 1) psum += __shfl_xor(psum, k);
    #pragma unroll
    for (int k = 1; k < 64; k <<= 1) tsum += __shfl_xor(tsum, k);

    if (lane == 0) out[b] = -(psum + tsum - log_norm);
}

extern "C" void kernel_launch(void* const* d_in, const int* in_sizes, int n_in,
                              void* d_out, int out_size, void* d_ws, size_t ws_size,
                              hipStream_t stream) {
    const float* y_true = (const float*)d_in[0];
    const float* y_pred = (const float*)d_in[1];
    const float* trans  = (const float*)d_in[2];
    float* outp         = (float*)d_out;
    crf_nll_kernel<<<dim3(Bc), dim3(Lc), 0, stream>>>(y_true, y_pred, trans, outp);
}

// Round 9
// 172.069 us; speedup vs baseline: 1.2427x; 1.1532x over previous
//
#include <hip/hip_runtime.h>
#include <hip/hip_bf16.h>
#include <cstdint>
#include <cstddef>

// CRF NLL forward. B=256, T=512, L=64.
// R9: chunked parallel scan for occupancy (R3/R6/R8 all ~125us proved the
// 1-wave-per-CU serial chain is latency-bound; MfmaUtil 5%).
// Pass 1: 2048 waves (8 chunks x 256 batches, 8 waves/CU). Each computes its
//   chunk's 64x64 transfer matrix G_k = Prod_t diag(F_t) E^T via per-step
//   64x64x64 MFMA GEMM (32 mfma/step), with the R6/R8-verified sigma mapping
//   rho(K,8q+j)=4q+(j&3)+16((j>>2)+2K) absorbed into stationary A so the
//   D->B repack is pure per-lane. kappa fold + rsub0 drift renorm (R8).
//   Stores G^T in bf16 (8KB) + (c,psum,tsum) partials to ws.
// Pass 2: 256 waves; alpha0 through G_0..G_7 with the verbatim R6 vector
//   MFMA loop; combines partials; writes out.
// Chunk k covers steps/rows [64k+1 .. min(64k+64,511)]; row-0 point score in
// pass 2; transition carries from boundary rows 64k.

constexpr int Bc = 256, Tc = 512, Lc = 64;
#define LOG64F 4.1588830833596715f
#define WS_SCAL_OFF (16u << 20)

typedef __attribute__((ext_vector_type(8))) short v8s;   // 8 bf16
typedef __attribute__((ext_vector_type(4))) float v4f;
typedef __attribute__((ext_vector_type(4))) unsigned int v4u;
typedef __attribute__((ext_vector_type(2))) unsigned int v2u;

__device__ __forceinline__ float lane_bcast(float v, int lane) {
    return __uint_as_float(__builtin_amdgcn_readlane(__float_as_uint(v), lane));
}
__device__ __forceinline__ int lane_bcast_i(int v, int lane) {
    return __builtin_amdgcn_readlane(v, lane);
}
__device__ __forceinline__ unsigned pk2(float x, float y) {
    __hip_bfloat162 h = __float22bfloat162_rn(make_float2(x, y));
    unsigned r; __builtin_memcpy(&r, &h, 4); return r;
}
__device__ __forceinline__ v8s as_v8s(v4u u) {
    v8s r; __builtin_memcpy(&r, &u, 16); return r;
}

// ---------------- Pass 1 ----------------
__global__ __launch_bounds__(256, 2) void crf_pass1(
    const float* __restrict__ y_true,
    const float* __restrict__ y_pred,
    const float* __restrict__ trans,
    unsigned short* __restrict__ wsm,
    float* __restrict__ wss)
{
    const int tid = threadIdx.x, lane = tid & 63, wv = tid >> 6;
    const int w = blockIdx.x * 4 + wv;
    const int batch = w >> 3, chunk = w & 7;
    const int q = lane >> 4, m16 = lane & 15;
    const int rsub = q, csub = m16;

    __shared__ float strans[Lc * Lc];
    __shared__ alignas(16) float fbuf[4][2][4][Lc];

    {   // stage trans with all 256 threads
        const v4f* t4 = (const v4f*)trans;
        #pragma unroll
        for (int k = 0; k < 4; ++k) {
            v4f v = t4[k * 256 + tid];
            *(v4f*)&strans[(k * 256 + tid) * 4] = v;
        }
    }
    __syncthreads();

    // Stationary A: Af[I][K] elem jj = exp(trans[sig][16I+m16]),
    // sig = (jj&3)+4q+16(jj>>2)+32K   (verified R6 mapping)
    v8s Af[4][2];
    #pragma unroll
    for (int I = 0; I < 4; ++I) {
        #pragma unroll
        for (int K = 0; K < 2; ++K) {
            float e[8];
            #pragma unroll
            for (int jj = 0; jj < 8; ++jj) {
                const int sig = (jj & 3) + 4 * q + 16 * (jj >> 2) + 32 * K;
                e[jj] = __expf(strans[sig * Lc + 16 * I + m16]);
            }
            v4u u;
            u.x = pk2(e[0], e[1]); u.y = pk2(e[2], e[3]);
            u.z = pk2(e[4], e[5]); u.w = pk2(e[6], e[7]);
            Af[I][K] = as_v8s(u);
        }
    }

    const float* yp = y_pred + (size_t)batch * Tc * Lc;
    const float* yt = y_true + (size_t)batch * Tc * Lc;
    const v4f* yp4 = (const v4f*)yp;
    const v4f* yt4 = (const v4f*)yt;

    const int base = chunk * 64;          // boundary row
    int lbl_carry;
    {
        const float bt = yt[base * Lc + lane];
        lbl_carry = (int)__builtin_ctzll(__ballot(bt > 0.5f));
    }
    float psum = 0.0f, tsum = 0.0f, c = 0.0f;

    auto ld4 = [&](const v4f* p, int baseRow) -> v4f {
        int r = baseRow + rsub; r = (r < Tc - 1) ? r : (Tc - 1);
        return p[r * 16 + csub];
    };

    const int r0 = base + 1;
    v4f cyp = ld4(yp4, r0),     cyt = ld4(yt4, r0);
    v4f nyp = ld4(yp4, r0 + 4), nyt = ld4(yt4, r0 + 4);
    v4f myp = ld4(yp4, r0 + 8), myt = ld4(yt4, r0 + 8);

    {   // prologue F rows r0..r0+3 (all real for every chunk)
        const float k0 = lane_bcast(cyp.x, 0)  + LOG64F;
        const float k1 = lane_bcast(cyp.x, 16) + LOG64F;
        const float k2 = lane_bcast(cyp.x, 32) + LOG64F;
        const float k3 = lane_bcast(cyp.x, 48) + LOG64F;
        c += ((k0 + k1) + (k2 + k3));
        const float kk = (rsub & 1) ? ((rsub & 2) ? k3 : k1)
                                    : ((rsub & 2) ? k2 : k0);
        v4f f;
        f.x = __expf(cyp.x - kk); f.y = __expf(cyp.y - kk);
        f.z = __expf(cyp.z - kk); f.w = __expf(cyp.w - kk);
        *(v4f*)&fbuf[wv][0][rsub][4 * csub] = f;
    }

    // B = Identity in rho-slot layout
    v8s Bfr[2][4];
    #pragma unroll
    for (int K = 0; K < 2; ++K) {
        #pragma unroll
        for (int J = 0; J < 4; ++J) {
            v8s bb;
            #pragma unroll
            for (int jj = 0; jj < 8; ++jj) {
                const bool one = (csub == 4 * q + (jj & 3)) && (J == (jj >> 2) + 2 * K);
                bb[jj] = one ? (short)0x3F80 : (short)0;
            }
            Bfr[K][J] = bb;
        }
    }

    const v4f z4 = {0.f, 0.f, 0.f, 0.f};
    v4f P[4][4];
    #pragma unroll
    for (int I = 0; I < 4; ++I) {
        #pragma unroll
        for (int J = 0; J < 4; ++J) P[I][J] = z4;
    }
    int par = 0;

    // one matrix step: N <- diag(F) * (E^T * N)
    auto mstep = [&](int s) {
        v4f F[4];
        #pragma unroll
        for (int I = 0; I < 4; ++I)
            F[I] = *(const v4f*)&fbuf[wv][par][s][16 * I + 4 * q];
        #pragma unroll
        for (int I = 0; I < 4; ++I) {
            #pragma unroll
            for (int J = 0; J < 4; ++J) {
                v4f a = __builtin_amdgcn_mfma_f32_16x16x32_bf16(Af[I][0], Bfr[0][J], z4, 0, 0, 0);
                a = __builtin_amdgcn_mfma_f32_16x16x32_bf16(Af[I][1], Bfr[1][J], a, 0, 0, 0);
                P[I][J] = a * F[I];
            }
        }
        #pragma unroll
        for (int K = 0; K < 2; ++K) {
            #pragma unroll
            for (int J = 0; J < 4; ++J) {
                v4u u;
                u.x = pk2(P[2 * K][J].x,     P[2 * K][J].y);
                u.y = pk2(P[2 * K][J].z,     P[2 * K][J].w);
                u.z = pk2(P[2 * K + 1][J].x, P[2 * K + 1][J].y);
                u.w = pk2(P[2 * K + 1][J].z, P[2 * K + 1][J].w);
                Bfr[K][J] = as_v8s(u);
            }
        }
    };

    auto scores4 = [&]() {
        psum = fmaf(cyp.x, cyt.x, psum); psum = fmaf(cyp.y, cyt.y, psum);
        psum = fmaf(cyp.z, cyt.z, psum); psum = fmaf(cyp.w, cyt.w, psum);
        const float has = fmaxf(fmaxf(cyt.x, cyt.y), fmaxf(cyt.z, cyt.w));
        int lidx = 0;
        lidx = (cyt.y > 0.5f) ? 1 : lidx;
        lidx = (cyt.z > 0.5f) ? 2 : lidx;
        lidx = (cyt.w > 0.5f) ? 3 : lidx;
        const unsigned long long m = __ballot(has > 0.5f);
        const int ln0 = (int)__builtin_ctz((unsigned)(m & 0xFFFFull));
        const int ln1 = (int)__builtin_ctz((unsigned)((m >> 16) & 0xFFFFull));
        const int ln2 = (int)__builtin_ctz((unsigned)((m >> 32) & 0xFFFFull));
        const int ln3 = (int)__builtin_ctz((unsigned)(m >> 48));
        const int lbl0 = 4 * ln0 + lane_bcast_i(lidx, ln0);
        const int lbl1 = 4 * ln1 + lane_bcast_i(lidx, 16 + ln1);
        const int lbl2 = 4 * ln2 + lane_bcast_i(lidx, 32 + ln2);
        const int lbl3 = 4 * ln3 + lane_bcast_i(lidx, 48 + ln3);
        const int lpA = (rsub & 2) ? lbl1 : lbl_carry;
        const int lpB = (rsub & 2) ? lbl2 : lbl0;
        const int lp  = (rsub & 1) ? lpB : lpA;
        lbl_carry = lbl3;
        const v4f tr = *(const v4f*)&strans[lp * Lc + 4 * csub];
        tsum = fmaf(cyt.x, tr.x, tsum); tsum = fmaf(cyt.y, tr.y, tsum);
        tsum = fmaf(cyt.z, tr.z, tsum); tsum = fmaf(cyt.w, tr.w, tsum);
    };

    #pragma unroll 1
    for (int bi = 0; bi < 15; ++bi) {
        const int rb = r0 + 4 * bi;
        const v4f lyp = ld4(yp4, rb + 12), lyt = ld4(yt4, rb + 12);
        scores4();
        mstep(0); mstep(1); mstep(2); mstep(3);
        {   // postamble: drift (rsub0 row only) + F rows rb+4..rb+7
            const float sc = lane_bcast(P[0][0].x, 0);
            const float inv_s = 1.0f / sc;
            c += __logf(sc);
            const float k0 = lane_bcast(nyp.x, 0)  + LOG64F;
            const float k1 = lane_bcast(nyp.x, 16) + LOG64F;
            const float k2 = lane_bcast(nyp.x, 32) + LOG64F;
            const float k3 = lane_bcast(nyp.x, 48) + LOG64F;
            c += ((k0 + k1) + k2);
            if (rb + 7 <= Tc - 1) c += k3;   // phantom row-512 guard (chunk 7)
            const float kk = (rsub & 1) ? ((rsub & 2) ? k3 : k1)
                                        : ((rsub & 2) ? k2 : k0);
            const float sc0 = (rsub == 0) ? inv_s : 1.0f;
            v4f f;
            f.x = __expf(nyp.x - kk) * sc0; f.y = __expf(nyp.y - kk) * sc0;
            f.z = __expf(nyp.z - kk) * sc0; f.w = __expf(nyp.w - kk) * sc0;
            *(v4f*)&fbuf[wv][par ^ 1][rsub][4 * csub] = f;
        }
        par ^= 1;
        cyp = nyp; cyt = nyt; nyp = myp; nyt = myt; myp = lyp; myt = lyt;
    }

    if (chunk < 7) {            // 4 real tail steps, no postamble
        scores4();
        mstep(0); mstep(1); mstep(2); mstep(3);
    } else {                    // 3 real tail steps (rows 509..511), rsub3 phantom
        {
            float pd = cyp.x * cyt.x;
            pd = fmaf(cyp.y, cyt.y, pd); pd = fmaf(cyp.z, cyt.z, pd); pd = fmaf(cyp.w, cyt.w, pd);
            const float has = fmaxf(fmaxf(cyt.x, cyt.y), fmaxf(cyt.z, cyt.w));
            int lidx = 0;
            lidx = (cyt.y > 0.5f) ? 1 : lidx;
            lidx = (cyt.z > 0.5f) ? 2 : lidx;
            lidx = (cyt.w > 0.5f) ? 3 : lidx;
            const unsigned long long m = __ballot(has > 0.5f);
            const int ln0 = (int)__builtin_ctz((unsigned)(m & 0xFFFFull));
            const int ln1 = (int)__builtin_ctz((unsigned)((m >> 16) & 0xFFFFull));
            const int lbl0 = 4 * ln0 + lane_bcast_i(lidx, ln0);
            const int lbl1 = 4 * ln1 + lane_bcast_i(lidx, 16 + ln1);
            const int lpA = (rsub & 2) ? lbl1 : lbl_carry;
            const int lp  = (rsub & 1) ? lbl0 : lpA;
            const v4f tr = *(const v4f*)&strans[lp * Lc + 4 * csub];
            float td = cyt.x * tr.x;
            td = fmaf(cyt.y, tr.y, td); td = fmaf(cyt.z, tr.z, td); td = fmaf(cyt.w, tr.w, td);
            if (rsub < 3) { psum += pd; tsum += td; }
        }
        mstep(0); mstep(1); mstep(2);
    }

    // store H = G^T row-major bf16: H[16J+csub][16I+4q .. +3]
    unsigned short* hout = wsm + (size_t)(batch * 8 + chunk) * 4096;
    #pragma unroll
    for (int I = 0; I < 4; ++I) {
        #pragma unroll
        for (int J = 0; J < 4; ++J) {
            v2u u2;
            u2.x = pk2(P[I][J].x, P[I][J].y);
            u2.y = pk2(P[I][J].z, P[I][J].w);
            *(v2u*)(hout + (16 * J + csub) * 64 + 16 * I + 4 * q) = u2;
        }
    }
    #pragma unroll
    for (int k = 1; k < 64; k <<= 1) psum += __shfl_xor(psum, k);
    #pragma unroll
    for (int k = 1; k < 64; k <<= 1) tsum += __shfl_xor(tsum, k);
    if (lane == 0) {
        float* s = wss + (batch * 8 + chunk) * 4;
        s[0] = c; s[1] = psum; s[2] = tsum;
    }
}

// ---------------- Pass 2 ----------------
__global__ __launch_bounds__(256, 1) void crf_pass2(
    const float* __restrict__ y_true,
    const float* __restrict__ y_pred,
    const unsigned short* __restrict__ wsm,
    const float* __restrict__ wss,
    float* __restrict__ out)
{
    const int tid = threadIdx.x, lane = tid & 63, wv = tid >> 6;
    const int b = blockIdx.x * 4 + wv;
    const int q = lane >> 4, m16 = lane & 15;

    __shared__ unsigned short hmat[4][4096];
    __shared__ float arow[4][Lc];

    const float* yp = y_pred + (size_t)b * Tc * Lc;
    const float* yt = y_true + (size_t)b * Tc * Lc;
    const float yp0 = yp[lane], yt0 = yt[lane];
    float psum = yp0 * yt0, tsum = 0.0f;
    float c = lane_bcast(yp0, 0);
    arow[wv][lane] = __expf(yp0 - c);

    // initial B frags from alpha0 (verbatim R6 pack; sigma slots)
    v8s Bfr[2];
    #pragma unroll
    for (int cc = 0; cc < 2; ++cc) {
        const v4f lo = *(const v4f*)&arow[wv][32 * cc + 4 * q];
        const v4f hi = *(const v4f*)&arow[wv][32 * cc + 16 + 4 * q];
        v4u u;
        u.x = pk2(lo.x, lo.y); u.y = pk2(lo.z, lo.w);
        u.z = pk2(hi.x, hi.y); u.w = pk2(hi.z, hi.w);
        Bfr[cc] = as_v8s(u);
    }

    const v4f z4 = {0.f, 0.f, 0.f, 0.f};
    v4f P0 = z4, P1 = z4, P2 = z4, P3 = z4;

    #pragma unroll 1
    for (int kk = 0; kk < 8; ++kk) {
        // stage G^T (8 KB bf16) into LDS
        const v4u* src = (const v4u*)(wsm + (size_t)(b * 8 + kk) * 4096);
        #pragma unroll
        for (int i = 0; i < 8; ++i)
            *(v4u*)&hmat[wv][(i * 64 + lane) * 8] = src[i * 64 + lane];

        // A frags: A[I][K] elem jj = G[16I+m16][sig] = H[sig][16I+m16]
        v8s Afr[4][2];
        #pragma unroll
        for (int I = 0; I < 4; ++I) {
            #pragma unroll
            for (int K = 0; K < 2; ++K) {
                v4u u;
                #pragma unroll
                for (int p = 0; p < 4; ++p) {
                    const int jj = 2 * p;
                    const int sig = (jj & 3) + 4 * q + 16 * (jj >> 2) + 32 * K;
                    const unsigned h0 = hmat[wv][sig * 64 + 16 * I + m16];
                    const unsigned h1 = hmat[wv][(sig + 1) * 64 + 16 * I + m16];
                    u[p] = h0 | (h1 << 16);
                }
                Afr[I][K] = as_v8s(u);
            }
        }

        v4f a0 = __builtin_amdgcn_mfma_f32_16x16x32_bf16(Afr[0][0], Bfr[0], z4, 0, 0, 0);
        v4f a1 = __builtin_amdgcn_mfma_f32_16x16x32_bf16(Afr[1][0], Bfr[0], z4, 0, 0, 0);
        v4f a2 = __builtin_amdgcn_mfma_f32_16x16x32_bf16(Afr[2][0], Bfr[0], z4, 0, 0, 0);
        v4f a3 = __builtin_amdgcn_mfma_f32_16x16x32_bf16(Afr[3][0], Bfr[0], z4, 0, 0, 0);
        a0 = __builtin_amdgcn_mfma_f32_16x16x32_bf16(Afr[0][1], Bfr[1], a0, 0, 0, 0);
        a1 = __builtin_amdgcn_mfma_f32_16x16x32_bf16(Afr[1][1], Bfr[1], a1, 0, 0, 0);
        a2 = __builtin_amdgcn_mfma_f32_16x16x32_bf16(Afr[2][1], Bfr[1], a2, 0, 0, 0);
        a3 = __builtin_amdgcn_mfma_f32_16x16x32_bf16(Afr[3][1], Bfr[1], a3, 0, 0, 0);

        const float sc = lane_bcast(a0.x, 0);
        const float inv = 1.0f / sc;
        c += __logf(sc);
        P0 = a0 * inv; P1 = a1 * inv; P2 = a2 * inv; P3 = a3 * inv;
        {
            v4u u;
            u.x = pk2(P0.x, P0.y); u.y = pk2(P0.z, P0.w);
            u.z = pk2(P1.x, P1.y); u.w = pk2(P1.z, P1.w);
            Bfr[0] = as_v8s(u);
        }
        {
            v4u u;
            u.x = pk2(P2.x, P2.y); u.y = pk2(P2.z, P2.w);
            u.z = pk2(P3.x, P3.y); u.w = pk2(P3.z, P3.w);
            Bfr[1] = as_v8s(u);
        }
    }

    float ftot = (((P0.x + P0.y) + (P0.z + P0.w)) + ((P1.x + P1.y) + (P1.z + P1.w)))
               + (((P2.x + P2.y) + (P2.z + P2.w)) + ((P3.x + P3.y) + (P3.z + P3.w)));
    ftot += __shfl_xor(ftot, 16);
    ftot += __shfl_xor(ftot, 32);

    #pragma unroll
    for (int k = 1; k < 64; k <<= 1) psum += __shfl_xor(psum, k);
    #pragma unroll
    for (int k = 1; k < 64; k <<= 1) tsum += __shfl_xor(tsum, k);

    if (lane == 0) {
        float cs = c, ps = psum, ts = tsum;
        #pragma unroll
        for (int kk = 0; kk < 8; ++kk) {
            const float* s = wss + (b * 8 + kk) * 4;
            cs += s[0]; ps += s[1]; ts += s[2];
        }
        out[b] = -(ps + ts - (cs + __logf(ftot)));
    }
}

extern "C" void kernel_launch(void* const* d_in, const int* in_sizes, int n_in,
                              void* d_out, int out_size, void* d_ws, size_t ws_size,
                              hipStream_t stream) {
    const float* y_true = (const float*)d_in[0];
    const float* y_pred = (const float*)d_in[1];
    const float* trans  = (const float*)d_in[2];
    float* outp = (float*)d_out;
    unsigned short* wsm = (unsigned short*)d_ws;
    float* wss = (float*)((char*)d_ws + WS_SCAL_OFF);
    crf_pass1<<<dim3(512), dim3(256), 0, stream>>>(y_true, y_pred, trans, wsm, wss);
    crf_pass2<<<dim3(64), dim3(256), 0, stream>>>(y_true, y_pred, wsm, wss, outp);
}

// Round 10
// 166.341 us; speedup vs baseline: 1.2855x; 1.0344x over previous
//
#include <hip/hip_runtime.h>
#include <hip/hip_bf16.h>
#include <cstdint>
#include <cstddef>

// CRF NLL forward. B=256, T=512, L=64.
// R10: pass1 J-split (2 waves x 32 cols per chunk -> 4096 waves, 16/CU),
// kappa-only normalization (no data-dependent drift correction inside a
// chunk: deterministic -> both halves consistent with zero sync; pass2's
// per-chunk rescale absorbs residual drift; |drift| << fp32 range).
// A-frags served from block-shared LDS blob (cuts ~32 VGPRs).
// G stored to ws directly in pass2's A-fragment order (per-lane 16B), so
// pass2 = 8 coalesced dwordx4 loads + 8 MFMAs per matrix, prefetched.

constexpr int Bc = 256, Tc = 512, Lc = 64;
#define LOG64F 4.1588830833596715f
#define WS_SCAL_OFF (16u << 20)

typedef __attribute__((ext_vector_type(8))) short v8s;   // 8 bf16
typedef __attribute__((ext_vector_type(4))) float v4f;
typedef __attribute__((ext_vector_type(4))) unsigned int v4u;

__device__ __forceinline__ float lane_bcast(float v, int lane) {
    return __uint_as_float(__builtin_amdgcn_readlane(__float_as_uint(v), lane));
}
__device__ __forceinline__ int lane_bcast_i(int v, int lane) {
    return __builtin_amdgcn_readlane(v, lane);
}
__device__ __forceinline__ unsigned pk2(float x, float y) {
    __hip_bfloat162 h = __float22bfloat162_rn(make_float2(x, y));
    unsigned r; __builtin_memcpy(&r, &h, 4); return r;
}
__device__ __forceinline__ v8s as_v8s(v4u u) {
    v8s r; __builtin_memcpy(&r, &u, 16); return r;
}
__device__ __forceinline__ unsigned short bf16b(float x) {
    __hip_bfloat16 h = __float2bfloat16(x);
    unsigned short r; __builtin_memcpy(&r, &h, 2); return r;
}

// ---------------- Pass 1 ----------------
__global__ __launch_bounds__(256, 4) void crf_pass1(
    const float* __restrict__ y_true,
    const float* __restrict__ y_pred,
    const float* __restrict__ trans,
    unsigned short* __restrict__ wsm,
    float* __restrict__ wss)
{
    const int tid = threadIdx.x, lane = tid & 63, wv = tid >> 6;
    const int w = blockIdx.x * 4 + wv;
    const int batch = w >> 4, chunk = (w >> 1) & 7, h = w & 1;
    const int q = lane >> 4, m16 = lane & 15;
    const int rsub = q, csub = m16;

    __shared__ alignas(16) unsigned char smem_raw[16384];  // strans, then G blob
    float* strans = (float*)smem_raw;
    __shared__ alignas(16) float fbuf[4][2][4][Lc];        // 8 KB
    __shared__ alignas(16) unsigned short Ablob[8 * 64 * 8]; // 8 KB bf16 A-operands

    {   // stage trans with all 256 threads
        const v4f* t4 = (const v4f*)trans;
        #pragma unroll
        for (int k = 0; k < 4; ++k) {
            v4f v = t4[k * 256 + tid];
            *(v4f*)&strans[(k * 256 + tid) * 4] = v;
        }
    }
    __syncthreads();

    // Build A-operand blob (shared per block; E = exp(trans)). Wave wv builds I=wv.
    #pragma unroll
    for (int K = 0; K < 2; ++K) {
        float e[8];
        #pragma unroll
        for (int jj = 0; jj < 8; ++jj) {
            const int sig = (jj & 3) + 4 * q + 16 * (jj >> 2) + 32 * K;
            e[jj] = __expf(strans[sig * Lc + 16 * wv + m16]);
        }
        v4u u;
        u.x = pk2(e[0], e[1]); u.y = pk2(e[2], e[3]);
        u.z = pk2(e[4], e[5]); u.w = pk2(e[6], e[7]);
        *(v4u*)&Ablob[((wv * 2 + K) * 64 + lane) * 8] = u;
    }
    __syncthreads();

    const float* yp = y_pred + (size_t)batch * Tc * Lc;
    const float* yt = y_true + (size_t)batch * Tc * Lc;
    const v4f* yp4 = (const v4f*)yp;
    const v4f* yt4 = (const v4f*)yt;

    const int base = chunk * 64;          // boundary row
    const int r0 = base + 1;
    float psum = 0.0f, tsum = 0.0f, c = 0.0f;
    int lbl_carry = 0;
    if (h == 0) {
        const float bt = yt[base * Lc + lane];
        lbl_carry = (int)__builtin_ctzll(__ballot(bt > 0.5f));
    }

    auto ld4 = [&](const v4f* p, int baseRow) -> v4f {
        int r = baseRow + rsub; r = (r < Tc - 1) ? r : (Tc - 1);
        return p[r * 16 + csub];
    };

    const v4f z4 = {0.f, 0.f, 0.f, 0.f};
    v4f cyp = ld4(yp4, r0), nyp = ld4(yp4, r0 + 4);
    v4f cyt = z4, nyt = z4;
    if (h == 0) { cyt = ld4(yt4, r0); nyt = ld4(yt4, r0 + 4); }

    {   // prologue F rows r0..r0+3 (kappa-only)
        const float k0 = lane_bcast(cyp.x, 0)  + LOG64F;
        const float k1 = lane_bcast(cyp.x, 16) + LOG64F;
        const float k2 = lane_bcast(cyp.x, 32) + LOG64F;
        const float k3 = lane_bcast(cyp.x, 48) + LOG64F;
        c += ((k0 + k1) + (k2 + k3));
        const float kk = (rsub & 1) ? ((rsub & 2) ? k3 : k1)
                                    : ((rsub & 2) ? k2 : k0);
        v4f f;
        f.x = __expf(cyp.x - kk); f.y = __expf(cyp.y - kk);
        f.z = __expf(cyp.z - kk); f.w = __expf(cyp.w - kk);
        *(v4f*)&fbuf[wv][0][rsub][4 * csub] = f;
    }

    // B = identity columns Jg = 2h + Jl
    v8s Bfr[2][2];
    #pragma unroll
    for (int Kc = 0; Kc < 2; ++Kc) {
        #pragma unroll
        for (int Jl = 0; Jl < 2; ++Jl) {
            v8s bb;
            #pragma unroll
            for (int jj = 0; jj < 8; ++jj) {
                const bool one = (m16 == 4 * q + (jj & 3)) &&
                                 (2 * h + Jl == (jj >> 2) + 2 * Kc);
                bb[jj] = one ? (short)0x3F80 : (short)0;
            }
            Bfr[Kc][Jl] = bb;
        }
    }

    v4f P[4][2];
    #pragma unroll
    for (int I = 0; I < 4; ++I) { P[I][0] = z4; P[I][1] = z4; }
    int par = 0;

    auto mstep = [&](int s) {
        #pragma unroll
        for (int I = 0; I < 4; ++I) {
            const v4f F = *(const v4f*)&fbuf[wv][par][s][16 * I + 4 * q];
            const v8s A0 = as_v8s(*(const v4u*)&Ablob[((I * 2 + 0) * 64 + lane) * 8]);
            const v8s A1 = as_v8s(*(const v4u*)&Ablob[((I * 2 + 1) * 64 + lane) * 8]);
            #pragma unroll
            for (int Jl = 0; Jl < 2; ++Jl) {
                v4f a = __builtin_amdgcn_mfma_f32_16x16x32_bf16(A0, Bfr[0][Jl], z4, 0, 0, 0);
                a = __builtin_amdgcn_mfma_f32_16x16x32_bf16(A1, Bfr[1][Jl], a, 0, 0, 0);
                P[I][Jl] = a * F;
            }
        }
        #pragma unroll
        for (int Kc = 0; Kc < 2; ++Kc) {
            #pragma unroll
            for (int Jl = 0; Jl < 2; ++Jl) {
                v4u u;
                u.x = pk2(P[2 * Kc][Jl].x,     P[2 * Kc][Jl].y);
                u.y = pk2(P[2 * Kc][Jl].z,     P[2 * Kc][Jl].w);
                u.z = pk2(P[2 * Kc + 1][Jl].x, P[2 * Kc + 1][Jl].y);
                u.w = pk2(P[2 * Kc + 1][Jl].z, P[2 * Kc + 1][Jl].w);
                Bfr[Kc][Jl] = as_v8s(u);
            }
        }
    };

    auto scores4 = [&]() {
        psum = fmaf(cyp.x, cyt.x, psum); psum = fmaf(cyp.y, cyt.y, psum);
        psum = fmaf(cyp.z, cyt.z, psum); psum = fmaf(cyp.w, cyt.w, psum);
        const float has = fmaxf(fmaxf(cyt.x, cyt.y), fmaxf(cyt.z, cyt.w));
        int lidx = 0;
        lidx = (cyt.y > 0.5f) ? 1 : lidx;
        lidx = (cyt.z > 0.5f) ? 2 : lidx;
        lidx = (cyt.w > 0.5f) ? 3 : lidx;
        const unsigned long long m = __ballot(has > 0.5f);
        const int ln0 = (int)__builtin_ctz((unsigned)(m & 0xFFFFull));
        const int ln1 = (int)__builtin_ctz((unsigned)((m >> 16) & 0xFFFFull));
        const int ln2 = (int)__builtin_ctz((unsigned)((m >> 32) & 0xFFFFull));
        const int ln3 = (int)__builtin_ctz((unsigned)(m >> 48));
        const int lbl0 = 4 * ln0 + lane_bcast_i(lidx, ln0);
        const int lbl1 = 4 * ln1 + lane_bcast_i(lidx, 16 + ln1);
        const int lbl2 = 4 * ln2 + lane_bcast_i(lidx, 32 + ln2);
        const int lbl3 = 4 * ln3 + lane_bcast_i(lidx, 48 + ln3);
        const int lpA = (rsub & 2) ? lbl1 : lbl_carry;
        const int lpB = (rsub & 2) ? lbl2 : lbl0;
        const int lp  = (rsub & 1) ? lpB : lpA;
        lbl_carry = lbl3;
        const v4f tr = *(const v4f*)&strans[lp * Lc + 4 * csub];
        tsum = fmaf(cyt.x, tr.x, tsum); tsum = fmaf(cyt.y, tr.y, tsum);
        tsum = fmaf(cyt.z, tr.z, tsum); tsum = fmaf(cyt.w, tr.w, tsum);
    };

    #pragma unroll 1
    for (int bi = 0; bi < 15; ++bi) {
        const int rb = r0 + 4 * bi;
        const v4f lyp = ld4(yp4, rb + 8);
        v4f lyt = z4;
        if (h == 0) lyt = ld4(yt4, rb + 8);

        if (h == 0) scores4();
        mstep(0); mstep(1); mstep(2); mstep(3);

        {   // postamble: kappa-only F build for rows rb+4..rb+7
            const float k0 = lane_bcast(nyp.x, 0)  + LOG64F;
            const float k1 = lane_bcast(nyp.x, 16) + LOG64F;
            const float k2 = lane_bcast(nyp.x, 32) + LOG64F;
            const float k3 = lane_bcast(nyp.x, 48) + LOG64F;
            c += ((k0 + k1) + k2);
            if (rb + 7 <= Tc - 1) c += k3;          // phantom row-512 guard
            const float kk = (rsub & 1) ? ((rsub & 2) ? k3 : k1)
                                        : ((rsub & 2) ? k2 : k0);
            v4f f;
            f.x = __expf(nyp.x - kk); f.y = __expf(nyp.y - kk);
            f.z = __expf(nyp.z - kk); f.w = __expf(nyp.w - kk);
            *(v4f*)&fbuf[wv][par ^ 1][rsub][4 * csub] = f;
        }
        par ^= 1;
        cyp = nyp; nyp = lyp;
        if (h == 0) { cyt = nyt; nyt = lyt; }
    }

    if (chunk < 7) {
        if (h == 0) scores4();
        mstep(0); mstep(1); mstep(2); mstep(3);
    } else {
        if (h == 0) {   // 3 real tail rows (509..511), rsub3 phantom
            float pd = cyp.x * cyt.x;
            pd = fmaf(cyp.y, cyt.y, pd); pd = fmaf(cyp.z, cyt.z, pd); pd = fmaf(cyp.w, cyt.w, pd);
            const float has = fmaxf(fmaxf(cyt.x, cyt.y), fmaxf(cyt.z, cyt.w));
            int lidx = 0;
            lidx = (cyt.y > 0.5f) ? 1 : lidx;
            lidx = (cyt.z > 0.5f) ? 2 : lidx;
            lidx = (cyt.w > 0.5f) ? 3 : lidx;
            const unsigned long long m = __ballot(has > 0.5f);
            const int ln0 = (int)__builtin_ctz((unsigned)(m & 0xFFFFull));
            const int ln1 = (int)__builtin_ctz((unsigned)((m >> 16) & 0xFFFFull));
            const int lbl0 = 4 * ln0 + lane_bcast_i(lidx, ln0);
            const int lbl1 = 4 * ln1 + lane_bcast_i(lidx, 16 + ln1);
            const int lpA = (rsub & 2) ? lbl1 : lbl_carry;
            const int lp  = (rsub & 1) ? lbl0 : lpA;
            const v4f tr = *(const v4f*)&strans[lp * Lc + 4 * csub];
            float td = cyt.x * tr.x;
            td = fmaf(cyt.y, tr.y, td); td = fmaf(cyt.z, tr.z, td); td = fmaf(cyt.w, tr.w, td);
            if (rsub < 3) { psum += pd; tsum += td; }
        }
        mstep(0); mstep(1); mstep(2);
    }

    // ---- G store in pass2 A-frag order, via LDS scatter (strans now dead) ----
    __syncthreads();   // all waves done reading strans
    unsigned short* myblob = ((unsigned short*)smem_raw) + wv * 2048;
    #pragma unroll
    for (int I = 0; I < 4; ++I) {
        #pragma unroll
        for (int Jl = 0; Jl < 2; ++Jl) {
            float v[4] = {P[I][Jl].x, P[I][Jl].y, P[I][Jl].z, P[I][Jl].w};
            #pragma unroll
            for (int r = 0; r < 4; ++r) {
                const int li = I * 512 + (16 * (m16 >> 2) + 4 * q + r) * 8
                             + 4 * Jl + (m16 & 3);
                myblob[li] = bf16b(v[r]);
            }
        }
    }
    {   // coalesced copy-out: this wave's 4 KB
        const int I = lane >> 4;
        const unsigned short* src = myblob + lane * 32;
        unsigned short* dst = wsm + (size_t)(batch * 8 + chunk) * 4096
                            + I * 1024 + h * 512 + (lane & 15) * 32;
        #pragma unroll
        for (int t = 0; t < 4; ++t)
            *(v4u*)(dst + t * 8) = *(const v4u*)(src + t * 8);
    }

    if (h == 0) {
        #pragma unroll
        for (int k = 1; k < 64; k <<= 1) psum += __shfl_xor(psum, k);
        #pragma unroll
        for (int k = 1; k < 64; k <<= 1) tsum += __shfl_xor(tsum, k);
        if (lane == 0) {
            float* s = wss + (batch * 8 + chunk) * 4;
            s[0] = c; s[1] = psum; s[2] = tsum;
        }
    }
}

// ---------------- Pass 2 ----------------
__global__ __launch_bounds__(64, 1) void crf_pass2(
    const float* __restrict__ y_true,
    const float* __restrict__ y_pred,
    const unsigned short* __restrict__ wsm,
    const float* __restrict__ wss,
    float* __restrict__ out)
{
    const int lane = threadIdx.x;
    const int b = blockIdx.x;
    const int q = lane >> 4;

    __shared__ float arow[Lc];

    const float* yp = y_pred + (size_t)b * Tc * Lc;
    const float* yt = y_true + (size_t)b * Tc * Lc;
    const float yp0 = yp[lane], yt0 = yt[lane];
    float psum = yp0 * yt0, tsum = 0.0f;
    float c = lane_bcast(yp0, 0);
    arow[lane] = __expf(yp0 - c);
    (void)yt0;

    v8s Bfr[2];
    #pragma unroll
    for (int cc = 0; cc < 2; ++cc) {
        const v4f lo = *(const v4f*)&arow[32 * cc + 4 * q];
        const v4f hi = *(const v4f*)&arow[32 * cc + 16 + 4 * q];
        v4u u;
        u.x = pk2(lo.x, lo.y); u.y = pk2(lo.z, lo.w);
        u.z = pk2(hi.x, hi.y); u.w = pk2(hi.z, hi.w);
        Bfr[cc] = as_v8s(u);
    }

    const v4f z4 = {0.f, 0.f, 0.f, 0.f};
    v4f P0 = z4, P1 = z4, P2 = z4, P3 = z4;

    v4u Abuf[2][8];
    {
        const v4u* g0 = (const v4u*)(wsm + (size_t)(b * 8) * 4096);
        #pragma unroll
        for (int s = 0; s < 8; ++s) Abuf[0][s] = g0[s * 64 + lane];
    }

    #pragma unroll
    for (int kk = 0; kk < 8; ++kk) {
        const int cur = kk & 1, nxt = cur ^ 1;
        if (kk < 7) {
            const v4u* g1 = (const v4u*)(wsm + (size_t)(b * 8 + kk + 1) * 4096);
            #pragma unroll
            for (int s = 0; s < 8; ++s) Abuf[nxt][s] = g1[s * 64 + lane];
        }
        v4f a0 = __builtin_amdgcn_mfma_f32_16x16x32_bf16(as_v8s(Abuf[cur][0]), Bfr[0], z4, 0, 0, 0);
        v4f a1 = __builtin_amdgcn_mfma_f32_16x16x32_bf16(as_v8s(Abuf[cur][2]), Bfr[0], z4, 0, 0, 0);
        v4f a2 = __builtin_amdgcn_mfma_f32_16x16x32_bf16(as_v8s(Abuf[cur][4]), Bfr[0], z4, 0, 0, 0);
        v4f a3 = __builtin_amdgcn_mfma_f32_16x16x32_bf16(as_v8s(Abuf[cur][6]), Bfr[0], z4, 0, 0, 0);
        a0 = __builtin_amdgcn_mfma_f32_16x16x32_bf16(as_v8s(Abuf[cur][1]), Bfr[1], a0, 0, 0, 0);
        a1 = __builtin_amdgcn_mfma_f32_16x16x32_bf16(as_v8s(Abuf[cur][3]), Bfr[1], a1, 0, 0, 0);
        a2 = __builtin_amdgcn_mfma_f32_16x16x32_bf16(as_v8s(Abuf[cur][5]), Bfr[1], a2, 0, 0, 0);
        a3 = __builtin_amdgcn_mfma_f32_16x16x32_bf16(as_v8s(Abuf[cur][7]), Bfr[1], a3, 0, 0, 0);

        const float sc = lane_bcast(a0.x, 0);
        const float inv = 1.0f / sc;
        c += __logf(sc);
        P0 = a0 * inv; P1 = a1 * inv; P2 = a2 * inv; P3 = a3 * inv;
        {
            v4u u;
            u.x = pk2(P0.x, P0.y); u.y = pk2(P0.z, P0.w);
            u.z = pk2(P1.x, P1.y); u.w = pk2(P1.z, P1.w);
            Bfr[0] = as_v8s(u);
        }
        {
            v4u u;
            u.x = pk2(P2.x, P2.y); u.y = pk2(P2.z, P2.w);
            u.z = pk2(P3.x, P3.y); u.w = pk2(P3.z, P3.w);
            Bfr[1] = as_v8s(u);
        }
    }

    float ftot = (((P0.x + P0.y) + (P0.z + P0.w)) + ((P1.x + P1.y) + (P1.z + P1.w)))
               + (((P2.x + P2.y) + (P2.z + P2.w)) + ((P3.x + P3.y) + (P3.z + P3.w)));
    ftot += __shfl_xor(ftot, 16);
    ftot += __shfl_xor(ftot, 32);

    #pragma unroll
    for (int k = 1; k < 64; k <<= 1) psum += __shfl_xor(psum, k);

    if (lane == 0) {
        float cs = c, ps = psum, ts = tsum;
        #pragma unroll
        for (int kk = 0; kk < 8; ++kk) {
            const float* s = wss + (b * 8 + kk) * 4;
            cs += s[0]; ps += s[1]; ts += s[2];
        }
        out[b] = -(ps + ts - (cs + __logf(ftot)));
    }
}

extern "C" void kernel_launch(void* const* d_in, const int* in_sizes, int n_in,
                              void* d_out, int out_size, void* d_ws, size_t ws_size,
                              hipStream_t stream) {
    const float* y_true = (const float*)d_in[0];
    const float* y_pred = (const float*)d_in[1];
    const float* trans  = (const float*)d_in[2];
    float* outp = (float*)d_out;
    unsigned short* wsm = (unsigned short*)d_ws;
    float* wss = (float*)((char*)d_ws + WS_SCAL_OFF);
    crf_pass1<<<dim3(1024), dim3(256), 0, stream>>>(y_true, y_pred, trans, wsm, wss);
    crf_pass2<<<dim3(256), dim3(64), 0, stream>>>(y_true, y_pred, wsm, wss, outp);
}

// Round 11
// 166.133 us; speedup vs baseline: 1.2871x; 1.0012x over previous
//
#include <hip/hip_runtime.h>
#include <hip/hip_bf16.h>
#include <cstdint>
#include <cstddef>

// CRF NLL forward. B=256, T=512, L=64.
// R11 = R10 with the stationary A operands moved from LDS (Ablob) into
// registers. R10 counters showed the LDS pipe was the saturated resource:
// 12 ds_read_b128/wave-step (~61us of LDS pipe per CU) + 1.1M bank
// conflicts. Now 4 ds_read/step (F only). VGPR ~100 (4 waves/SIMD kept via
// __launch_bounds__(256,4)); LDS 24KB/block.
// Structure unchanged: pass1 J-split (2 waves x 32 cols per chunk, 4096
// waves), kappa-only normalization, G stored in pass2 A-frag order; pass2
// chains alpha0 through the 8 chunk matrices.

constexpr int Bc = 256, Tc = 512, Lc = 64;
#define LOG64F 4.1588830833596715f
#define WS_SCAL_OFF (16u << 20)

typedef __attribute__((ext_vector_type(8))) short v8s;   // 8 bf16
typedef __attribute__((ext_vector_type(4))) float v4f;
typedef __attribute__((ext_vector_type(4))) unsigned int v4u;

__device__ __forceinline__ float lane_bcast(float v, int lane) {
    return __uint_as_float(__builtin_amdgcn_readlane(__float_as_uint(v), lane));
}
__device__ __forceinline__ int lane_bcast_i(int v, int lane) {
    return __builtin_amdgcn_readlane(v, lane);
}
__device__ __forceinline__ unsigned pk2(float x, float y) {
    __hip_bfloat162 h = __float22bfloat162_rn(make_float2(x, y));
    unsigned r; __builtin_memcpy(&r, &h, 4); return r;
}
__device__ __forceinline__ v8s as_v8s(v4u u) {
    v8s r; __builtin_memcpy(&r, &u, 16); return r;
}
__device__ __forceinline__ unsigned short bf16b(float x) {
    __hip_bfloat16 h = __float2bfloat16(x);
    unsigned short r; __builtin_memcpy(&r, &h, 2); return r;
}

// ---------------- Pass 1 ----------------
__global__ __launch_bounds__(256, 4) void crf_pass1(
    const float* __restrict__ y_true,
    const float* __restrict__ y_pred,
    const float* __restrict__ trans,
    unsigned short* __restrict__ wsm,
    float* __restrict__ wss)
{
    const int tid = threadIdx.x, lane = tid & 63, wv = tid >> 6;
    const int w = blockIdx.x * 4 + wv;
    const int batch = w >> 4, chunk = (w >> 1) & 7, h = w & 1;
    const int q = lane >> 4, m16 = lane & 15;
    const int rsub = q, csub = m16;

    __shared__ alignas(16) unsigned char smem_raw[16384];  // strans, then G scatter
    float* strans = (float*)smem_raw;
    __shared__ alignas(16) float fbuf[4][2][4][Lc];        // 8 KB

    {   // stage trans with all 256 threads
        const v4f* t4 = (const v4f*)trans;
        #pragma unroll
        for (int k = 0; k < 4; ++k) {
            v4f v = t4[k * 256 + tid];
            *(v4f*)&strans[(k * 256 + tid) * 4] = v;
        }
    }
    __syncthreads();

    // Stationary A operands in REGISTERS (R11 change; was LDS Ablob in R10).
    // Areg[I][K] elem jj = exp(trans[sig][16I+m16]), sig=(jj&3)+4q+16(jj>>2)+32K.
    v8s Areg[4][2];
    #pragma unroll
    for (int I = 0; I < 4; ++I) {
        #pragma unroll
        for (int K = 0; K < 2; ++K) {
            float e[8];
            #pragma unroll
            for (int jj = 0; jj < 8; ++jj) {
                const int sig = (jj & 3) + 4 * q + 16 * (jj >> 2) + 32 * K;
                e[jj] = __expf(strans[sig * Lc + 16 * I + m16]);
            }
            v4u u;
            u.x = pk2(e[0], e[1]); u.y = pk2(e[2], e[3]);
            u.z = pk2(e[4], e[5]); u.w = pk2(e[6], e[7]);
            Areg[I][K] = as_v8s(u);
        }
    }

    const float* yp = y_pred + (size_t)batch * Tc * Lc;
    const float* yt = y_true + (size_t)batch * Tc * Lc;
    const v4f* yp4 = (const v4f*)yp;
    const v4f* yt4 = (const v4f*)yt;

    const int base = chunk * 64;          // boundary row
    const int r0 = base + 1;
    float psum = 0.0f, tsum = 0.0f, c = 0.0f;
    int lbl_carry = 0;
    if (h == 0) {
        const float bt = yt[base * Lc + lane];
        lbl_carry = (int)__builtin_ctzll(__ballot(bt > 0.5f));
    }

    auto ld4 = [&](const v4f* p, int baseRow) -> v4f {
        int r = baseRow + rsub; r = (r < Tc - 1) ? r : (Tc - 1);
        return p[r * 16 + csub];
    };

    const v4f z4 = {0.f, 0.f, 0.f, 0.f};
    v4f cyp = ld4(yp4, r0), nyp = ld4(yp4, r0 + 4);
    v4f cyt = z4, nyt = z4;
    if (h == 0) { cyt = ld4(yt4, r0); nyt = ld4(yt4, r0 + 4); }

    {   // prologue F rows r0..r0+3 (kappa-only)
        const float k0 = lane_bcast(cyp.x, 0)  + LOG64F;
        const float k1 = lane_bcast(cyp.x, 16) + LOG64F;
        const float k2 = lane_bcast(cyp.x, 32) + LOG64F;
        const float k3 = lane_bcast(cyp.x, 48) + LOG64F;
        c += ((k0 + k1) + (k2 + k3));
        const float kk = (rsub & 1) ? ((rsub & 2) ? k3 : k1)
                                    : ((rsub & 2) ? k2 : k0);
        v4f f;
        f.x = __expf(cyp.x - kk); f.y = __expf(cyp.y - kk);
        f.z = __expf(cyp.z - kk); f.w = __expf(cyp.w - kk);
        *(v4f*)&fbuf[wv][0][rsub][4 * csub] = f;
    }

    // B = identity columns Jg = 2h + Jl
    v8s Bfr[2][2];
    #pragma unroll
    for (int Kc = 0; Kc < 2; ++Kc) {
        #pragma unroll
        for (int Jl = 0; Jl < 2; ++Jl) {
            v8s bb;
            #pragma unroll
            for (int jj = 0; jj < 8; ++jj) {
                const bool one = (m16 == 4 * q + (jj & 3)) &&
                                 (2 * h + Jl == (jj >> 2) + 2 * Kc);
                bb[jj] = one ? (short)0x3F80 : (short)0;
            }
            Bfr[Kc][Jl] = bb;
        }
    }

    v4f P[4][2];
    #pragma unroll
    for (int I = 0; I < 4; ++I) { P[I][0] = z4; P[I][1] = z4; }
    int par = 0;

    auto mstep = [&](int s) {
        #pragma unroll
        for (int I = 0; I < 4; ++I) {
            const v4f F = *(const v4f*)&fbuf[wv][par][s][16 * I + 4 * q];
            #pragma unroll
            for (int Jl = 0; Jl < 2; ++Jl) {
                v4f a = __builtin_amdgcn_mfma_f32_16x16x32_bf16(Areg[I][0], Bfr[0][Jl], z4, 0, 0, 0);
                a = __builtin_amdgcn_mfma_f32_16x16x32_bf16(Areg[I][1], Bfr[1][Jl], a, 0, 0, 0);
                P[I][Jl] = a * F;
            }
        }
        #pragma unroll
        for (int Kc = 0; Kc < 2; ++Kc) {
            #pragma unroll
            for (int Jl = 0; Jl < 2; ++Jl) {
                v4u u;
                u.x = pk2(P[2 * Kc][Jl].x,     P[2 * Kc][Jl].y);
                u.y = pk2(P[2 * Kc][Jl].z,     P[2 * Kc][Jl].w);
                u.z = pk2(P[2 * Kc + 1][Jl].x, P[2 * Kc + 1][Jl].y);
                u.w = pk2(P[2 * Kc + 1][Jl].z, P[2 * Kc + 1][Jl].w);
                Bfr[Kc][Jl] = as_v8s(u);
            }
        }
    };

    auto scores4 = [&]() {
        psum = fmaf(cyp.x, cyt.x, psum); psum = fmaf(cyp.y, cyt.y, psum);
        psum = fmaf(cyp.z, cyt.z, psum); psum = fmaf(cyp.w, cyt.w, psum);
        const float has = fmaxf(fmaxf(cyt.x, cyt.y), fmaxf(cyt.z, cyt.w));
        int lidx = 0;
        lidx = (cyt.y > 0.5f) ? 1 : lidx;
        lidx = (cyt.z > 0.5f) ? 2 : lidx;
        lidx = (cyt.w > 0.5f) ? 3 : lidx;
        const unsigned long long m = __ballot(has > 0.5f);
        const int ln0 = (int)__builtin_ctz((unsigned)(m & 0xFFFFull));
        const int ln1 = (int)__builtin_ctz((unsigned)((m >> 16) & 0xFFFFull));
        const int ln2 = (int)__builtin_ctz((unsigned)((m >> 32) & 0xFFFFull));
        const int ln3 = (int)__builtin_ctz((unsigned)(m >> 48));
        const int lbl0 = 4 * ln0 + lane_bcast_i(lidx, ln0);
        const int lbl1 = 4 * ln1 + lane_bcast_i(lidx, 16 + ln1);
        const int lbl2 = 4 * ln2 + lane_bcast_i(lidx, 32 + ln2);
        const int lbl3 = 4 * ln3 + lane_bcast_i(lidx, 48 + ln3);
        const int lpA = (rsub & 2) ? lbl1 : lbl_carry;
        const int lpB = (rsub & 2) ? lbl2 : lbl0;
        const int lp  = (rsub & 1) ? lpB : lpA;
        lbl_carry = lbl3;
        const v4f tr = *(const v4f*)&strans[lp * Lc + 4 * csub];
        tsum = fmaf(cyt.x, tr.x, tsum); tsum = fmaf(cyt.y, tr.y, tsum);
        tsum = fmaf(cyt.z, tr.z, tsum); tsum = fmaf(cyt.w, tr.w, tsum);
    };

    #pragma unroll 1
    for (int bi = 0; bi < 15; ++bi) {
        const int rb = r0 + 4 * bi;
        const v4f lyp = ld4(yp4, rb + 8);
        v4f lyt = z4;
        if (h == 0) lyt = ld4(yt4, rb + 8);

        if (h == 0) scores4();
        mstep(0); mstep(1); mstep(2); mstep(3);

        {   // postamble: kappa-only F build for rows rb+4..rb+7
            const float k0 = lane_bcast(nyp.x, 0)  + LOG64F;
            const float k1 = lane_bcast(nyp.x, 16) + LOG64F;
            const float k2 = lane_bcast(nyp.x, 32) + LOG64F;
            const float k3 = lane_bcast(nyp.x, 48) + LOG64F;
            c += ((k0 + k1) + k2);
            if (rb + 7 <= Tc - 1) c += k3;          // phantom row-512 guard
            const float kk = (rsub & 1) ? ((rsub & 2) ? k3 : k1)
                                        : ((rsub & 2) ? k2 : k0);
            v4f f;
            f.x = __expf(nyp.x - kk); f.y = __expf(nyp.y - kk);
            f.z = __expf(nyp.z - kk); f.w = __expf(nyp.w - kk);
            *(v4f*)&fbuf[wv][par ^ 1][rsub][4 * csub] = f;
        }
        par ^= 1;
        cyp = nyp; nyp = lyp;
        if (h == 0) { cyt = nyt; nyt = lyt; }
    }

    if (chunk < 7) {
        if (h == 0) scores4();
        mstep(0); mstep(1); mstep(2); mstep(3);
    } else {
        if (h == 0) {   // 3 real tail rows (509..511), rsub3 phantom
            float pd = cyp.x * cyt.x;
            pd = fmaf(cyp.y, cyt.y, pd); pd = fmaf(cyp.z, cyt.z, pd); pd = fmaf(cyp.w, cyt.w, pd);
            const float has = fmaxf(fmaxf(cyt.x, cyt.y), fmaxf(cyt.z, cyt.w));
            int lidx = 0;
            lidx = (cyt.y > 0.5f) ? 1 : lidx;
            lidx = (cyt.z > 0.5f) ? 2 : lidx;
            lidx = (cyt.w > 0.5f) ? 3 : lidx;
            const unsigned long long m = __ballot(has > 0.5f);
            const int ln0 = (int)__builtin_ctz((unsigned)(m & 0xFFFFull));
            const int ln1 = (int)__builtin_ctz((unsigned)((m >> 16) & 0xFFFFull));
            const int lbl0 = 4 * ln0 + lane_bcast_i(lidx, ln0);
            const int lbl1 = 4 * ln1 + lane_bcast_i(lidx, 16 + ln1);
            const int lpA = (rsub & 2) ? lbl1 : lbl_carry;
            const int lp  = (rsub & 1) ? lbl0 : lpA;
            const v4f tr = *(const v4f*)&strans[lp * Lc + 4 * csub];
            float td = cyt.x * tr.x;
            td = fmaf(cyt.y, tr.y, td); td = fmaf(cyt.z, tr.z, td); td = fmaf(cyt.w, tr.w, td);
            if (rsub < 3) { psum += pd; tsum += td; }
        }
        mstep(0); mstep(1); mstep(2);
    }

    // ---- G store in pass2 A-frag order, via LDS scatter (strans now dead) ----
    __syncthreads();   // all waves done reading strans
    unsigned short* myblob = ((unsigned short*)smem_raw) + wv * 2048;
    #pragma unroll
    for (int I = 0; I < 4; ++I) {
        #pragma unroll
        for (int Jl = 0; Jl < 2; ++Jl) {
            float v[4] = {P[I][Jl].x, P[I][Jl].y, P[I][Jl].z, P[I][Jl].w};
            #pragma unroll
            for (int r = 0; r < 4; ++r) {
                const int li = I * 512 + (16 * (m16 >> 2) + 4 * q + r) * 8
                             + 4 * Jl + (m16 & 3);
                myblob[li] = bf16b(v[r]);
            }
        }
    }
    {   // coalesced copy-out: this wave's 4 KB
        const int I = lane >> 4;
        const unsigned short* src = myblob + lane * 32;
        unsigned short* dst = wsm + (size_t)(batch * 8 + chunk) * 4096
                            + I * 1024 + h * 512 + (lane & 15) * 32;
        #pragma unroll
        for (int t = 0; t < 4; ++t)
            *(v4u*)(dst + t * 8) = *(const v4u*)(src + t * 8);
    }

    if (h == 0) {
        #pragma unroll
        for (int k = 1; k < 64; k <<= 1) psum += __shfl_xor(psum, k);
        #pragma unroll
        for (int k = 1; k < 64; k <<= 1) tsum += __shfl_xor(tsum, k);
        if (lane == 0) {
            float* s = wss + (batch * 8 + chunk) * 4;
            s[0] = c; s[1] = psum; s[2] = tsum;
        }
    }
}

// ---------------- Pass 2 ----------------
__global__ __launch_bounds__(64, 1) void crf_pass2(
    const float* __restrict__ y_true,
    const float* __restrict__ y_pred,
    const unsigned short* __restrict__ wsm,
    const float* __restrict__ wss,
    float* __restrict__ out)
{
    const int lane = threadIdx.x;
    const int b = blockIdx.x;
    const int q = lane >> 4;

    __shared__ float arow[Lc];

    const float* yp = y_pred + (size_t)b * Tc * Lc;
    const float* yt = y_true + (size_t)b * Tc * Lc;
    const float yp0 = yp[lane], yt0 = yt[lane];
    float psum = yp0 * yt0, tsum = 0.0f;
    float c = lane_bcast(yp0, 0);
    arow[lane] = __expf(yp0 - c);
    (void)yt0;

    v8s Bfr[2];
    #pragma unroll
    for (int cc = 0; cc < 2; ++cc) {
        const v4f lo = *(const v4f*)&arow[32 * cc + 4 * q];
        const v4f hi = *(const v4f*)&arow[32 * cc + 16 + 4 * q];
        v4u u;
        u.x = pk2(lo.x, lo.y); u.y = pk2(lo.z, lo.w);
        u.z = pk2(hi.x, hi.y); u.w = pk2(hi.z, hi.w);
        Bfr[cc] = as_v8s(u);
    }

    const v4f z4 = {0.f, 0.f, 0.f, 0.f};
    v4f P0 = z4, P1 = z4, P2 = z4, P3 = z4;

    v4u Abuf[2][8];
    {
        const v4u* g0 = (const v4u*)(wsm + (size_t)(b * 8) * 4096);
        #pragma unroll
        for (int s = 0; s < 8; ++s) Abuf[0][s] = g0[s * 64 + lane];
    }

    #pragma unroll
    for (int kk = 0; kk < 8; ++kk) {
        const int cur = kk & 1, nxt = cur ^ 1;
        if (kk < 7) {
            const v4u* g1 = (const v4u*)(wsm + (size_t)(b * 8 + kk + 1) * 4096);
            #pragma unroll
            for (int s = 0; s < 8; ++s) Abuf[nxt][s] = g1[s * 64 + lane];
        }
        v4f a0 = __builtin_amdgcn_mfma_f32_16x16x32_bf16(as_v8s(Abuf[cur][0]), Bfr[0], z4, 0, 0, 0);
        v4f a1 = __builtin_amdgcn_mfma_f32_16x16x32_bf16(as_v8s(Abuf[cur][2]), Bfr[0], z4, 0, 0, 0);
        v4f a2 = __builtin_amdgcn_mfma_f32_16x16x32_bf16(as_v8s(Abuf[cur][4]), Bfr[0], z4, 0, 0, 0);
        v4f a3 = __builtin_amdgcn_mfma_f32_16x16x32_bf16(as_v8s(Abuf[cur][6]), Bfr[0], z4, 0, 0, 0);
        a0 = __builtin_amdgcn_mfma_f32_16x16x32_bf16(as_v8s(Abuf[cur][1]), Bfr[1], a0, 0, 0, 0);
        a1 = __builtin_amdgcn_mfma_f32_16x16x32_bf16(as_v8s(Abuf[cur][3]), Bfr[1], a1, 0, 0, 0);
        a2 = __builtin_amdgcn_mfma_f32_16x16x32_bf16(as_v8s(Abuf[cur][5]), Bfr[1], a2, 0, 0, 0);
        a3 = __builtin_amdgcn_mfma_f32_16x16x32_bf16(as_v8s(Abuf[cur][7]), Bfr[1], a3, 0, 0, 0);

        const float sc = lane_bcast(a0.x, 0);
        const float inv = 1.0f / sc;
        c += __logf(sc);
        P0 = a0 * inv; P1 = a1 * inv; P2 = a2 * inv; P3 = a3 * inv;
        {
            v4u u;
            u.x = pk2(P0.x, P0.y); u.y = pk2(P0.z, P0.w);
            u.z = pk2(P1.x, P1.y); u.w = pk2(P1.z, P1.w);
            Bfr[0] = as_v8s(u);
        }
        {
            v4u u;
            u.x = pk2(P2.x, P2.y); u.y = pk2(P2.z, P2.w);
            u.z = pk2(P3.x, P3.y); u.w = pk2(P3.z, P3.w);
            Bfr[1] = as_v8s(u);
        }
    }

    float ftot = (((P0.x + P0.y) + (P0.z + P0.w)) + ((P1.x + P1.y) + (P1.z + P1.w)))
               + (((P2.x + P2.y) + (P2.z + P2.w)) + ((P3.x + P3.y) + (P3.z + P3.w)));
    ftot += __shfl_xor(ftot, 16);
    ftot += __shfl_xor(ftot, 32);

    #pragma unroll
    for (int k = 1; k < 64; k <<= 1) psum += __shfl_xor(psum, k);

    if (lane == 0) {
        float cs = c, ps = psum, ts = tsum;
        #pragma unroll
        for (int kk = 0; kk < 8; ++kk) {
            const float* s = wss + (b * 8 + kk) * 4;
            cs += s[0]; ps += s[1]; ts += s[2];
        }
        out[b] = -(ps + ts - (cs + __logf(ftot)));
    }
}

extern "C" void kernel_launch(void* const* d_in, const int* in_sizes, int n_in,
                              void* d_out, int out_size, void* d_ws, size_t ws_size,
                              hipStream_t stream) {
    const float* y_true = (const float*)d_in[0];
    const float* y_pred = (const float*)d_in[1];
    const float* trans  = (const float*)d_in[2];
    float* outp = (float*)d_out;
    unsigned short* wsm = (unsigned short*)d_ws;
    float* wss = (float*)((char*)d_ws + WS_SCAL_OFF);
    crf_pass1<<<dim3(1024), dim3(256), 0, stream>>>(y_true, y_pred, trans, wsm, wss);
    crf_pass2<<<dim3(256), dim3(64), 0, stream>>>(y_true, y_pred, wsm, wss, outp);
}